// Round 14
// baseline (263.673 us; speedup 1.0000x reference)
//
#include <hip/hip_runtime.h>
#include <hip/hip_bf16.h>
#include <math.h>

typedef __hip_bfloat16 bf16;
typedef __attribute__((ext_vector_type(8))) short short8;
typedef __attribute__((ext_vector_type(16))) float floatx16;

// Problem constants
constexpr int B_   = 2;
constexpr int T_   = 8;
constexpr int HW   = 48 * 48;          // 2304
constexpr int S_   = T_ * HW;          // 18432
constexpr int D_   = 64;
constexpr int NH   = 4;
constexpr int DH   = 16;
constexpr int M_   = 32;
constexpr int BS   = B_ * S_;          // 36864 tokens
constexpr int BSD  = BS * D_;          // 2359296
constexpr int BH   = B_ * NH;          // 8 sequences
constexpr int BHS  = BH * S_;          // 147456 rows
constexpr int BHSM = BHS * M_;         // 4718592
constexpr int CHUNK = 32;
constexpr int NC   = S_ / CHUNK;       // 576 chunks per sequence
constexpr int STATE = M_ * DH + M_;    // 544 floats of scan state
constexpr float DN = 0.5f;                         // 16^-0.25
constexpr float RATIO = 0.17677669529663687f;      // 32^-0.5

__device__ __forceinline__ unsigned short f2bf(float f) {
  bf16 h = __float2bfloat16(f);
  return *reinterpret_cast<unsigned short*>(&h);
}
// monotone float<->uint encoding for atomicMax over signed floats
__device__ __forceinline__ unsigned encmax(float f) {
  unsigned u = __float_as_uint(f);
  return (u & 0x80000000u) ? ~u : (u | 0x80000000u);
}
__device__ __forceinline__ float decmax(unsigned e) {
  unsigned u = (e & 0x80000000u) ? (e ^ 0x80000000u) : ~e;
  return __uint_as_float(u);
}

// ---------------- fused: 1x1x1 conv3d + softplus + LayerNorm1 (+ ws inits) ----------------
__global__ void k_preln(const float* __restrict__ x, const float* __restrict__ pw,
                        const float* __restrict__ pb, const float* __restrict__ g,
                        const float* __restrict__ bb,
                        float* __restrict__ tok, float* __restrict__ h,
                        float* __restrict__ partial, unsigned* __restrict__ gmaxu) {
  if (blockIdx.x == 0) {
    if (threadIdx.x < 130) partial[threadIdx.x] = 0.f;
    if (threadIdx.x == 200) gmaxu[0] = 0u;
  }
  int token = blockIdx.x * 4 + (threadIdx.x >> 6);
  int lane = threadIdx.x & 63;
  int f = token * 64 + lane;          // flat over B*D*S
  int b = f / (D_ * S_);
  int r = f % (D_ * S_);
  int d = r / S_;
  int pos = r % S_;
  const float* xb = x + b * 3 * S_ + pos;
  float a = xb[0] * pw[d * 3 + 0] + xb[S_] * pw[d * 3 + 1] + xb[2 * S_] * pw[d * 3 + 2]
          + pb[d];
  float t = fmaxf(a, 0.f) + log1pf(expf(-fabsf(a)));  // softplus
  tok[f] = t;
  float s1 = t, s2 = t * t;
  for (int off = 32; off; off >>= 1) {
    s1 += __shfl_xor(s1, off);
    s2 += __shfl_xor(s2, off);
  }
  float mu = s1 * (1.f / 64.f);
  float var = s2 * (1.f / 64.f) - mu * mu;
  float rs = rsqrtf(var + 1e-5f);
  h[f] = (t - mu) * rs * g[lane] + bb[lane];
}

// ---------------- QKV projections via MFMA: 3 waves = {wq,wk,wv}, 32 tokens/block ----------------
__global__ void __launch_bounds__(192) k_qkv(const float* __restrict__ h,
                      const float* __restrict__ wq, const float* __restrict__ wk,
                      const float* __restrict__ wv,
                      float* __restrict__ q, float* __restrict__ k, float* __restrict__ v) {
  int tid = threadIdx.x;
  int w = tid >> 6;                 // wave -> matrix
  int L = tid & 63;
  int half = L >> 5;
  int n = L & 31;
  int tbase = blockIdx.x * 32;
  const float* wm = (w == 0) ? wq : (w == 1) ? wk : wv;
  float* outm = (w == 0) ? q : (w == 1) ? k : v;

  short8 a[4];
  {
    const float* hrow = h + (size_t)(tbase + n) * 64 + half * 8;
#pragma unroll
    for (int c = 0; c < 4; ++c) {
      float4 f0 = *(const float4*)&hrow[c * 16];
      float4 f1 = *(const float4*)&hrow[c * 16 + 4];
      a[c][0] = (short)f2bf(f0.x); a[c][1] = (short)f2bf(f0.y);
      a[c][2] = (short)f2bf(f0.z); a[c][3] = (short)f2bf(f0.w);
      a[c][4] = (short)f2bf(f1.x); a[c][5] = (short)f2bf(f1.y);
      a[c][6] = (short)f2bf(f1.z); a[c][7] = (short)f2bf(f1.w);
    }
  }
#pragma unroll
  for (int ct = 0; ct < 2; ++ct) {
    int col = ct * 32 + n;
    short8 bfrag[4];
#pragma unroll
    for (int c = 0; c < 4; ++c) {
#pragma unroll
      for (int j = 0; j < 8; ++j)
        bfrag[c][j] = (short)f2bf(wm[(c * 16 + half * 8 + j) * 64 + col]);
    }
    floatx16 acc;
#pragma unroll
    for (int i = 0; i < 16; ++i) acc[i] = 0.f;
    acc = __builtin_amdgcn_mfma_f32_32x32x16_bf16(a[0], bfrag[0], acc, 0, 0, 0);
    acc = __builtin_amdgcn_mfma_f32_32x32x16_bf16(a[1], bfrag[1], acc, 0, 0, 0);
    acc = __builtin_amdgcn_mfma_f32_32x32x16_bf16(a[2], bfrag[2], acc, 0, 0, 0);
    acc = __builtin_amdgcn_mfma_f32_32x32x16_bf16(a[3], bfrag[3], acc, 0, 0, 0);
    int head = col >> 4, di = col & 15;
#pragma unroll
    for (int r = 0; r < 16; ++r) {
      int row = (r & 3) + 8 * (r >> 2) + 4 * half;
      int token = tbase + row;
      int b = token / S_, s = token % S_;
      outm[((size_t)(b * NH + head) * S_ + s) * DH + di] = acc[r];
    }
  }
}

// ---------------- feature map: qp (bf16, final) + k-dash block max -> atomic gmax ----------------
__global__ void __launch_bounds__(64) k_feat(const float* __restrict__ q,
                      const float* __restrict__ k, const float* __restrict__ proj,
                      bf16* __restrict__ qpb, unsigned* __restrict__ gmaxu) {
  __shared__ __align__(16) float sPT[16 * 32];   // proj^T [d][m]
  int tid = threadIdx.x;
  for (int e = tid; e < 512; e += 64) {
    int d = e >> 5, m = e & 31;
    sPT[d * 32 + m] = proj[m * 16 + d];
  }
  __syncthreads();
  int row = blockIdx.x * 64 + tid;
  float qv[16], kv[16];
  float dq = 0.f;
  {
    const float4* q4 = (const float4*)(q + (size_t)row * 16);
    const float4* k4 = (const float4*)(k + (size_t)row * 16);
#pragma unroll
    for (int i = 0; i < 4; ++i) {
      float4 t4 = q4[i];
      qv[4*i] = t4.x * DN; qv[4*i+1] = t4.y * DN; qv[4*i+2] = t4.z * DN; qv[4*i+3] = t4.w * DN;
      float4 u4 = k4[i];
      kv[4*i] = u4.x * DN; kv[4*i+1] = u4.y * DN; kv[4*i+2] = u4.z * DN; kv[4*i+3] = u4.w * DN;
    }
#pragma unroll
    for (int d = 0; d < 16; ++d) dq += qv[d] * qv[d];
    dq *= 0.5f;
  }
  float accq[32], acck[32];
#pragma unroll
  for (int m = 0; m < 32; ++m) { accq[m] = 0.f; acck[m] = 0.f; }
#pragma unroll
  for (int d = 0; d < 16; ++d) {
    float qd = qv[d], kd = kv[d];
    const float4* pr = (const float4*)&sPT[d * 32];
#pragma unroll
    for (int m4 = 0; m4 < 8; ++m4) {
      float4 p = pr[m4];
      accq[4*m4+0] += qd * p.x; accq[4*m4+1] += qd * p.y;
      accq[4*m4+2] += qd * p.z; accq[4*m4+3] += qd * p.w;
      acck[4*m4+0] += kd * p.x; acck[4*m4+1] += kd * p.y;
      acck[4*m4+2] += kd * p.z; acck[4*m4+3] += kd * p.w;
    }
  }
  float mx = accq[0];
#pragma unroll
  for (int m = 1; m < 32; ++m) mx = fmaxf(mx, accq[m]);
#pragma unroll
  for (int m8 = 0; m8 < 4; ++m8) {
    float o[8];
#pragma unroll
    for (int j = 0; j < 8; ++j)
      o[j] = RATIO * (expf(accq[m8 * 8 + j] - dq - mx) + 1e-4f);
    uint4 pk;
    pk.x = (unsigned)f2bf(o[0]) | ((unsigned)f2bf(o[1]) << 16);
    pk.y = (unsigned)f2bf(o[2]) | ((unsigned)f2bf(o[3]) << 16);
    pk.z = (unsigned)f2bf(o[4]) | ((unsigned)f2bf(o[5]) << 16);
    pk.w = (unsigned)f2bf(o[6]) | ((unsigned)f2bf(o[7]) << 16);
    *(uint4*)&qpb[(size_t)row * 32 + m8 * 8] = pk;
  }
  float bmax = acck[0];
#pragma unroll
  for (int m = 1; m < 32; ++m) bmax = fmaxf(bmax, acck[m]);
  for (int off = 32; off; off >>= 1) bmax = fmaxf(bmax, __shfl_xor(bmax, off));
  if (tid == 0) atomicMax(gmaxu, encmax(bmax));
}

// ---------------- dash recompute + kp-finalize (bf16) + per-chunk sums ----------------
__global__ void __launch_bounds__(256) k_csfin(const float* __restrict__ k,
                      const float* __restrict__ v, const float* __restrict__ proj,
                      const unsigned* __restrict__ gmaxu,
                      bf16* __restrict__ kpb, float* __restrict__ ckv) {
  __shared__ float sK[32 * 17];                   // k chunk, stride 17 (conflict-free)
  __shared__ __align__(16) float sPT[16 * 32];    // proj^T
  __shared__ float sKp[32 * 33];                  // finalized kp, stride 33
  __shared__ __align__(16) float sVc[32 * 16];
  int blk = blockIdx.x;
  int bh = blk / NC, c = blk % NC;
  int tid = threadIdx.x;
  int base = bh * S_ + c * CHUNK;
  for (int e = tid; e < 512; e += 256) {
    int d = e >> 5, m = e & 31;
    sPT[d * 32 + m] = proj[m * 16 + d];
  }
  if (tid < 128) {
    int row = tid >> 2, c4 = tid & 3;
    float4 kf = *(const float4*)&k[(size_t)(base + row) * 16 + c4 * 4];
    sK[row * 17 + c4 * 4 + 0] = kf.x;
    sK[row * 17 + c4 * 4 + 1] = kf.y;
    sK[row * 17 + c4 * 4 + 2] = kf.z;
    sK[row * 17 + c4 * 4 + 3] = kf.w;
    float4 vf = *(const float4*)&v[(size_t)(base + row) * 16 + c4 * 4];
    *(float4*)&sVc[row * 16 + c4 * 4] = vf;
  }
  __syncthreads();
  float gm = decmax(gmaxu[0]);
  {
    int row = tid >> 3, mq = (tid & 7) * 4;
    float dk = 0.f, d0 = 0.f, d1 = 0.f, d2 = 0.f, d3 = 0.f;
#pragma unroll
    for (int d = 0; d < 16; ++d) {
      float kd = sK[row * 17 + d] * DN;
      dk += kd * kd;
      const float4 p = *(const float4*)&sPT[d * 32 + mq];
      d0 += kd * p.x; d1 += kd * p.y; d2 += kd * p.z; d3 += kd * p.w;
    }
    dk *= 0.5f;
    float f0 = RATIO * (expf(d0 - dk - gm) + 1e-4f);
    float f1 = RATIO * (expf(d1 - dk - gm) + 1e-4f);
    float f2 = RATIO * (expf(d2 - dk - gm) + 1e-4f);
    float f3 = RATIO * (expf(d3 - dk - gm) + 1e-4f);
    uint2 u;
    u.x = (unsigned)f2bf(f0) | ((unsigned)f2bf(f1) << 16);
    u.y = (unsigned)f2bf(f2) | ((unsigned)f2bf(f3) << 16);
    *(uint2*)&kpb[(size_t)(base + row) * 32 + mq] = u;
    sKp[row * 33 + mq + 0] = f0;
    sKp[row * 33 + mq + 1] = f1;
    sKp[row * 33 + mq + 2] = f2;
    sKp[row * 33 + mq + 3] = f3;
  }
  __syncthreads();
  int m0 = tid >> 4, d0i = tid & 15;
  int m1 = m0 + 16;
  float a0 = 0.f, a1 = 0.f, az0 = 0.f, az1 = 0.f;
  for (int t = 0; t < CHUNK; ++t) {
    float k0 = sKp[t * 33 + m0];
    float k1 = sKp[t * 33 + m1];
    float vv = sVc[t * 16 + d0i];
    a0 += k0 * vv;
    a1 += k1 * vv;
    if (d0i == 0) { az0 += k0; az1 += k1; }
  }
  float* outp = ckv + (size_t)blk * STATE;
  outp[m0 * 16 + d0i] = a0;
  outp[m1 * 16 + d0i] = a1;
  if (d0i == 0) { outp[512 + m0] = az0; outp[512 + m1] = az1; }
}

// ---------------- exclusive prefix over chunks (in place), one scan-column per thread ----------------
__global__ void k_prefix(float* __restrict__ ckv) {
  int idx = blockIdx.x * 256 + threadIdx.x;      // 17 blocks x 256 = 4352 = BH*544
  int bh = idx / STATE, c = idx % STATE;
  float run = 0.f;
  for (int j0 = 0; j0 < NC; j0 += 16) {
    float tb[16];
#pragma unroll
    for (int jj = 0; jj < 16; ++jj) tb[jj] = ckv[((size_t)bh * NC + j0 + jj) * STATE + c];
#pragma unroll
    for (int jj = 0; jj < 16; ++jj) {
      ckv[((size_t)bh * NC + j0 + jj) * STATE + c] = run;
      run += tb[jj];
    }
  }
}

// ---------------- within-chunk causal attention via MFMA (CHUNK=32; 4 chunks/block) ----------------
__global__ void __launch_bounds__(256) k_attn(const bf16* __restrict__ qpb,
                                              const bf16* __restrict__ kpb,
                                              const float* __restrict__ v,
                                              const float* __restrict__ ckv,
                                              float* __restrict__ attn) {
  __shared__ __align__(16) float sP[4][32 * 33 + 4];
  int tid = threadIdx.x;
  int w = tid >> 6;                 // wave -> chunk
  int L = tid & 63;
  int half = L >> 5;
  int n = L & 31;
  int chunk = blockIdx.x * 4 + w;
  int bh = chunk / NC, c = chunk % NC;
  int base = bh * S_ + c * CHUNK;

  short8 a1 = *(const short8*)(qpb + (size_t)(base + n) * 32 + half * 8);
  short8 a2 = *(const short8*)(qpb + (size_t)(base + n) * 32 + 16 + half * 8);
  short8 b1 = *(const short8*)(kpb + (size_t)(base + n) * 32 + half * 8);
  short8 b2 = *(const short8*)(kpb + (size_t)(base + n) * 32 + 16 + half * 8);

  floatx16 P;
#pragma unroll
  for (int i = 0; i < 16; ++i) P[i] = 0.f;
  P = __builtin_amdgcn_mfma_f32_32x32x16_bf16(a1, b1, P, 0, 0, 0);
  P = __builtin_amdgcn_mfma_f32_32x32x16_bf16(a2, b2, P, 0, 0, 0);

  float* sp = &sP[w][0];
#pragma unroll
  for (int r = 0; r < 16; ++r) {
    int i = (r & 3) + 8 * (r >> 2) + 4 * half;
    sp[i * 33 + n] = (n <= i) ? P[r] : 0.f;
  }
  __syncthreads();
  short8 pa1, pa2;
#pragma unroll
  for (int j = 0; j < 8; ++j) {
    pa1[j] = (short)f2bf(sp[n * 33 + half * 8 + j]);
    pa2[j] = (short)f2bf(sp[n * 33 + 16 + half * 8 + j]);
  }

  const float* cs = ckv + (size_t)chunk * STATE;
  short8 vb1, vb2, sb1, sb2;
#pragma unroll
  for (int j = 0; j < 8; ++j) {
    int t1 = half * 8 + j, t2 = 16 + half * 8 + j;
    float x1 = (n < 16) ? v[(size_t)(base + t1) * 16 + n] : (n == 16 ? 1.f : 0.f);
    float x2 = (n < 16) ? v[(size_t)(base + t2) * 16 + n] : (n == 16 ? 1.f : 0.f);
    vb1[j] = (short)f2bf(x1);
    vb2[j] = (short)f2bf(x2);
    float y1 = (n < 16) ? cs[t1 * 16 + n] : (n == 16 ? cs[512 + t1] : 0.f);
    float y2 = (n < 16) ? cs[t2 * 16 + n] : (n == 16 ? cs[512 + t2] : 0.f);
    sb1[j] = (short)f2bf(y1);
    sb2[j] = (short)f2bf(y2);
  }

  floatx16 O;
#pragma unroll
  for (int i = 0; i < 16; ++i) O[i] = 0.f;
  O = __builtin_amdgcn_mfma_f32_32x32x16_bf16(pa1, vb1, O, 0, 0, 0);
  O = __builtin_amdgcn_mfma_f32_32x32x16_bf16(pa2, vb2, O, 0, 0, 0);
  O = __builtin_amdgcn_mfma_f32_32x32x16_bf16(a1, sb1, O, 0, 0, 0);
  O = __builtin_amdgcn_mfma_f32_32x32x16_bf16(a2, sb2, O, 0, 0, 0);

  int srcl = 16 + 32 * half;
  float res[16];
#pragma unroll
  for (int r = 0; r < 16; ++r) {
    float den = __shfl(O[r], srcl, 64);
    res[r] = O[r] / den;
  }
  if (n < 16) {
    int b = bh >> 2, head = bh & 3;
#pragma unroll
    for (int r = 0; r < 16; ++r) {
      int i = (r & 3) + 8 * (r >> 2) + 4 * half;
      attn[((size_t)(b * S_ + c * CHUNK + i)) * 64 + head * 16 + n] = res[r];
    }
  }
}

// ---------------- attn @ wo + bo + residual + LayerNorm2 via MFMA ----------------
__global__ void __launch_bounds__(128) k_wo_ln(const float* __restrict__ attn,
                        const float* __restrict__ wo, const float* __restrict__ bo,
                        const float* __restrict__ tok, const float* __restrict__ g,
                        const float* __restrict__ bb,
                        float* __restrict__ tok2, float* __restrict__ h2) {
  __shared__ __align__(16) float sC[32 * 68];
  int tid = threadIdx.x;
  int w = tid >> 6;                 // coltile
  int L = tid & 63;
  int half = L >> 5;
  int n = L & 31;
  int tbase = blockIdx.x * 32;

  short8 a[4];
  {
    const float* arow = attn + (size_t)(tbase + n) * 64 + half * 8;
#pragma unroll
    for (int c = 0; c < 4; ++c) {
      float4 f0 = *(const float4*)&arow[c * 16];
      float4 f1 = *(const float4*)&arow[c * 16 + 4];
      a[c][0] = (short)f2bf(f0.x); a[c][1] = (short)f2bf(f0.y);
      a[c][2] = (short)f2bf(f0.z); a[c][3] = (short)f2bf(f0.w);
      a[c][4] = (short)f2bf(f1.x); a[c][5] = (short)f2bf(f1.y);
      a[c][6] = (short)f2bf(f1.z); a[c][7] = (short)f2bf(f1.w);
    }
  }
  int col = w * 32 + n;
  short8 bfrag[4];
#pragma unroll
  for (int c = 0; c < 4; ++c) {
#pragma unroll
    for (int j = 0; j < 8; ++j)
      bfrag[c][j] = (short)f2bf(wo[(c * 16 + half * 8 + j) * 64 + col]);
  }
  floatx16 acc;
#pragma unroll
  for (int i = 0; i < 16; ++i) acc[i] = 0.f;
  acc = __builtin_amdgcn_mfma_f32_32x32x16_bf16(a[0], bfrag[0], acc, 0, 0, 0);
  acc = __builtin_amdgcn_mfma_f32_32x32x16_bf16(a[1], bfrag[1], acc, 0, 0, 0);
  acc = __builtin_amdgcn_mfma_f32_32x32x16_bf16(a[2], bfrag[2], acc, 0, 0, 0);
  acc = __builtin_amdgcn_mfma_f32_32x32x16_bf16(a[3], bfrag[3], acc, 0, 0, 0);
  float bias = bo[col];
#pragma unroll
  for (int r = 0; r < 16; ++r) {
    int row = (r & 3) + 8 * (r >> 2) + 4 * half;
    sC[row * 68 + col] = acc[r] + tok[(size_t)(tbase + row) * 64 + col] + bias;
  }
  __syncthreads();
  int tg = tid >> 5, cg = tid & 31;
  int c0 = cg * 2, c1 = c0 + 1;
  float g0 = g[c0], g1 = g[c1], be0 = bb[c0], be1 = bb[c1];
#pragma unroll
  for (int i = 0; i < 8; ++i) {
    int lrow = tg * 8 + i;
    int token = tbase + lrow;
    float t0 = sC[lrow * 68 + c0];
    float t1 = sC[lrow * 68 + c1];
    float s1 = t0 + t1, s2 = t0 * t0 + t1 * t1;
    for (int off = 16; off; off >>= 1) {
      s1 += __shfl_xor(s1, off, 32);
      s2 += __shfl_xor(s2, off, 32);
    }
    float mu = s1 * (1.f / 64.f);
    float var = s2 * (1.f / 64.f) - mu * mu;
    float rs = rsqrtf(var + 1e-5f);
    tok2[token * 64 + c0] = t0;
    tok2[token * 64 + c1] = t1;
    h2[token * 64 + c0] = (t0 - mu) * rs * g0 + be0;
    h2[token * 64 + c1] = (t1 - mu) * rs * g1 + be1;
  }
}

// ---------------- FF1 + Gavg fused via MFMA ----------------
__global__ void __launch_bounds__(256) k_ffg(const float* __restrict__ h2,
                                             const float* __restrict__ w1,
                                             const float* __restrict__ b1,
                                             float* __restrict__ Gavg) {
  int tid = threadIdx.x;
  int w = tid >> 6;
  int L = tid & 63;
  int half = L >> 5;
  int n = L & 31;
  int blk = blockIdx.x;                 // B*64*9 = 1152
  int b = blk / 576;
  int rem = blk % 576;
  int ch = rem / 9;
  int jp0 = (rem % 9) * 4;
  int token_n = b * 18432 + ch * 288 + (n & 7) * 36 + jp0 + (n >> 3);

  short8 a[4];
  {
    const float* hrow = h2 + (size_t)token_n * 64 + half * 8;
#pragma unroll
    for (int c = 0; c < 4; ++c) {
      float4 f0 = *(const float4*)&hrow[c * 16];
      float4 f1 = *(const float4*)&hrow[c * 16 + 4];
      a[c][0] = (short)f2bf(f0.x); a[c][1] = (short)f2bf(f0.y);
      a[c][2] = (short)f2bf(f0.z); a[c][3] = (short)f2bf(f0.w);
      a[c][4] = (short)f2bf(f1.x); a[c][5] = (short)f2bf(f1.y);
      a[c][6] = (short)f2bf(f1.z); a[c][7] = (short)f2bf(f1.w);
    }
  }
  size_t gbase = ((size_t)(b * 64 + ch) * 36 + jp0);
#pragma unroll
  for (int ct = 0; ct < 2; ++ct) {
    int col = w * 64 + ct * 32 + n;
    short8 bfrag[4];
#pragma unroll
    for (int c = 0; c < 4; ++c) {
#pragma unroll
      for (int j = 0; j < 8; ++j)
        bfrag[c][j] = (short)f2bf(w1[(c * 16 + half * 8 + j) * 256 + col]);
    }
    floatx16 acc;
#pragma unroll
    for (int i = 0; i < 16; ++i) acc[i] = 0.f;
    acc = __builtin_amdgcn_mfma_f32_32x32x16_bf16(a[0], bfrag[0], acc, 0, 0, 0);
    acc = __builtin_amdgcn_mfma_f32_32x32x16_bf16(a[1], bfrag[1], acc, 0, 0, 0);
    acc = __builtin_amdgcn_mfma_f32_32x32x16_bf16(a[2], bfrag[2], acc, 0, 0, 0);
    acc = __builtin_amdgcn_mfma_f32_32x32x16_bf16(a[3], bfrag[3], acc, 0, 0, 0);
    float bias = b1[col];
#pragma unroll
    for (int j = 0; j < 4; ++j) {          // jp_local
      float s = 0.f;
#pragma unroll
      for (int rr = 0; rr < 4; ++rr) {
        float xg = acc[j * 4 + rr] + bias;
        s += 0.5f * xg * (1.f + erff(xg * 0.70710678118654752f));
      }
      s += __shfl_xor(s, 32);              // combine lane-halves (t 0..3 | 4..7)
      if (half == 0)
        Gavg[(gbase + j) * 256 + col] = s * 0.125f;
    }
  }
}

// ---------------- pool+conv fused: partial[b*65+ch] += conv-weighted plane sum ----------------
__global__ void __launch_bounds__(256) k_poolc(const float* __restrict__ Gavg,
                        const float* __restrict__ tok2, const float* __restrict__ w2,
                        const float* __restrict__ b2, const float* __restrict__ tw,
                        float* __restrict__ partial) {
  __shared__ __align__(16) float sG[18 * 256];
  __shared__ __align__(16) float sRed[4 * 18 * 64];
  __shared__ float cls[25];
  __shared__ float red[256];
  int blk = blockIdx.x;
  int b = blk / 128;
  int rem = blk % 128;
  int ch = rem >> 1, jph = rem & 1;
  int tid = threadIdx.x;
  if (tid < 25) {
    int ry = tid / 5, rx = tid % 5;
    int kh0 = (ry <= 2) ? 0 : (ry == 3 ? 1 : 2);
    int kh1 = (ry >= 2) ? 4 : (ry == 1 ? 3 : 2);
    int kw0 = (rx <= 2) ? 0 : (rx == 3 ? 1 : 2);
    int kw1 = (rx >= 2) ? 4 : (rx == 1 ? 3 : 2);
    float s = 0.f;
    for (int kh = kh0; kh <= kh1; ++kh)
      for (int kw = kw0; kw <= kw1; ++kw)
        s += tw[ch * 25 + kh * 5 + kw];
    cls[tid] = s;
  }
  size_t grow0 = ((size_t)(b * 64 + ch) * 36 + jph * 18) * 256;
  for (int e = tid; e < 1152; e += 256) {
    int row = e >> 6, c4 = e & 63;
    *(float4*)&sG[row * 256 + c4 * 4] = *(const float4*)&Gavg[grow0 + row * 256 + c4 * 4];
  }
  __syncthreads();
  int kg = tid >> 6, dd = tid & 63;
  float acc[18];
#pragma unroll
  for (int i = 0; i < 18; ++i) acc[i] = 0.f;
  for (int k4 = 0; k4 < 16; ++k4) {
    int k = kg * 64 + k4 * 4;
    float w0 = w2[(k + 0) * 64 + dd];
    float w1 = w2[(k + 1) * 64 + dd];
    float w2v = w2[(k + 2) * 64 + dd];
    float w3 = w2[(k + 3) * 64 + dd];
#pragma unroll
    for (int i = 0; i < 18; ++i) {
      float4 gf = *(const float4*)&sG[i * 256 + k];
      acc[i] += gf.x * w0 + gf.y * w1 + gf.z * w2v + gf.w * w3;
    }
  }
#pragma unroll
  for (int i = 0; i < 18; ++i) sRed[(kg * 18 + i) * 64 + dd] = acc[i];
  __syncthreads();
  float csum = 0.f;
  for (int o = tid; o < 1152; o += 256) {
    int jp18 = o >> 6, d2 = o & 63;
    float gsum = sRed[(0 * 18 + jp18) * 64 + d2] + sRed[(1 * 18 + jp18) * 64 + d2]
               + sRed[(2 * 18 + jp18) * 64 + d2] + sRed[(3 * 18 + jp18) * 64 + d2];
    int p = (jph * 18 + jp18) * 64 + d2;
    size_t tbase = (size_t)b * 1179648 + (size_t)ch * 18432 + p;
    float ts = 0.f;
#pragma unroll
    for (int t = 0; t < 8; ++t) ts += tok2[tbase + t * 2304];
    float val = ts * 0.125f + gsum + b2[d2];
    int iy = p / 48, ix = p % 48;
    int ry = (iy == 0) ? 0 : (iy == 1) ? 1 : (iy <= 45) ? 2 : (iy == 46) ? 3 : 4;
    int rx = (ix == 0) ? 0 : (ix == 1) ? 1 : (ix <= 45) ? 2 : (ix == 46) ? 3 : 4;
    csum += val * cls[ry * 5 + rx];
  }
  red[tid] = csum;
  __syncthreads();
  for (int s = 128; s; s >>= 1) {
    if (tid < s) red[tid] += red[tid + s];
    __syncthreads();
  }
  if (!tid) atomicAdd(&partial[b * 65 + ch], red[0]);
}

// ---------------- final: x-channel conv term + reduce 65 sums + readout ----------------
__global__ void __launch_bounds__(128) k_final(const float* __restrict__ partial,
                        const float* __restrict__ x, const float* __restrict__ tw,
                        const float* __restrict__ tgt_b, const float* __restrict__ rd_w,
                        const float* __restrict__ rd_b, float* __restrict__ out) {
  __shared__ float cls[25];
  __shared__ float red[128];
  int b = blockIdx.x;
  int tid = threadIdx.x;
  if (tid < 25) {
    int ry = tid / 5, rx = tid % 5;
    int kh0 = (ry <= 2) ? 0 : (ry == 3 ? 1 : 2);
    int kh1 = (ry >= 2) ? 4 : (ry == 1 ? 3 : 2);
    int kw0 = (rx <= 2) ? 0 : (rx == 3 ? 1 : 2);
    int kw1 = (rx >= 2) ? 4 : (rx == 1 ? 3 : 2);
    float s = 0.f;
    for (int kh = kh0; kh <= kh1; ++kh)
      for (int kw = kw0; kw <= kw1; ++kw)
        s += tw[64 * 25 + kh * 5 + kw];
    cls[tid] = s;
  }
  __syncthreads();
  float xacc = 0.f;
  const float* xp = x + (size_t)b * 3 * S_ + 2 * S_;
  for (int e = tid; e < HW; e += 128) {
    int iy = e / 48, ix = e % 48;
    int ry = (iy == 0) ? 0 : (iy == 1) ? 1 : (iy <= 45) ? 2 : (iy == 46) ? 3 : 4;
    int rx = (ix == 0) ? 0 : (ix == 1) ? 1 : (ix <= 45) ? 2 : (ix == 46) ? 3 : 4;
    xacc += xp[e] * cls[ry * 5 + rx];
  }
  float valv = xacc + ((tid < 64) ? partial[b * 65 + tid] : 0.f);
  red[tid] = valv;
  __syncthreads();
  for (int s = 64; s; s >>= 1) {
    if (tid < s) red[tid] += red[tid + s];
    __syncthreads();
  }
  if (!tid) {
    float mean = red[0] / 2304.f + tgt_b[0];
    out[b] = mean * rd_w[0] + rd_b[0];
  }
}

extern "C" void kernel_launch(void* const* d_in, const int* in_sizes, int n_in,
                              void* d_out, int out_size, void* d_ws, size_t ws_size,
                              hipStream_t stream) {
  const float* x     = (const float*)d_in[0];
  const float* pre_w = (const float*)d_in[1];
  const float* pre_b = (const float*)d_in[2];
  const float* ln1_g = (const float*)d_in[3];
  const float* ln1_b = (const float*)d_in[4];
  const float* wq    = (const float*)d_in[5];
  const float* wk    = (const float*)d_in[6];
  const float* wv    = (const float*)d_in[7];
  const float* wo    = (const float*)d_in[8];
  const float* bo    = (const float*)d_in[9];
  const float* proj  = (const float*)d_in[10];
  const float* ln2_g = (const float*)d_in[11];
  const float* ln2_b = (const float*)d_in[12];
  const float* ff_w1 = (const float*)d_in[13];
  const float* ff_b1 = (const float*)d_in[14];
  const float* ff_w2 = (const float*)d_in[15];
  const float* ff_b2 = (const float*)d_in[16];
  const float* tgt_w = (const float*)d_in[17];
  const float* tgt_b = (const float*)d_in[18];
  const float* rd_w  = (const float*)d_in[19];
  const float* rd_b  = (const float*)d_in[20];
  float* out = (float*)d_out;

  float* ws = (float*)d_ws;
  // BSD-unit layout:
  // 0 tok | 1 v | 2 q (dead after feat) -> Gavg | 3 k/attnb
  // 4 h (dead after qkv) -> h2 (wo_ln) | 6 qpb (bf16) | 7 kpb (bf16)
  // 8 ckv (dead after attn) -> tok2 | 9+ smalls
  float* tok   = ws;
  float* v     = ws + (size_t)BSD;
  float* q     = ws + 2 * (size_t)BSD;
  float* Gavg  = ws + 2 * (size_t)BSD;          // q dead after k_feat
  float* k     = ws + 3 * (size_t)BSD;
  float* h     = ws + 4 * (size_t)BSD;          // LN1 out; dead after k_qkv
  bf16*  qpb   = (bf16*)(ws + 6 * (size_t)BSD); // BHSM bf16
  bf16*  kpb   = (bf16*)(ws + 7 * (size_t)BSD); // BHSM bf16
  float* ckv   = ws + 8 * (size_t)BSD;          // dead after k_attn
  float* tok2  = ws + 8 * (size_t)BSD;          // written by k_wo_ln (ckv dead)
  float* attnb = k;                             // k dead after k_csfin
  float* h2    = ws + 4 * (size_t)BSD;          // h dead after k_qkv
  float* smalls = ws + 9 * (size_t)BSD + 147456;
  unsigned* gmaxu = (unsigned*)smalls;          // 1
  float* partial  = smalls + 64;                // 130

  k_preln<<<dim3(BS / 4), dim3(256), 0, stream>>>(x, pre_w, pre_b, ln1_g, ln1_b, tok, h,
                                                  partial, gmaxu);
  k_qkv<<<dim3(BS / 32), dim3(192), 0, stream>>>(h, wq, wk, wv, q, k, v);
  k_feat<<<dim3(BHS / 64), dim3(64), 0, stream>>>(q, k, proj, qpb, gmaxu);
  k_csfin<<<dim3(BH * NC), dim3(256), 0, stream>>>(k, v, proj, gmaxu, kpb, ckv);
  k_prefix<<<dim3(BH * STATE / 256), dim3(256), 0, stream>>>(ckv);
  k_attn<<<dim3(BH * NC / 4), dim3(256), 0, stream>>>(qpb, kpb, v, ckv, attnb);
  k_wo_ln<<<dim3(BS / 32), dim3(128), 0, stream>>>(attnb, wo, bo, tok, ln2_g, ln2_b, tok2, h2);
  k_ffg<<<dim3(B_ * 64 * 9), dim3(256), 0, stream>>>(h2, ff_w1, ff_b1, Gavg);
  k_poolc<<<dim3(B_ * 64 * 2), dim3(256), 0, stream>>>(Gavg, tok2, ff_w2, ff_b2, tgt_w, partial);
  k_final<<<dim3(B_), dim3(128), 0, stream>>>(partial, x, tgt_w, tgt_b, rd_w, rd_b, out);
}

// Round 15
// 231.824 us; speedup vs baseline: 1.1374x; 1.1374x over previous
//
#include <hip/hip_runtime.h>
#include <hip/hip_bf16.h>
#include <math.h>

typedef __hip_bfloat16 bf16;
typedef __attribute__((ext_vector_type(8))) short short8;
typedef __attribute__((ext_vector_type(16))) float floatx16;

// Problem constants
constexpr int B_   = 2;
constexpr int T_   = 8;
constexpr int HW   = 48 * 48;          // 2304
constexpr int S_   = T_ * HW;          // 18432
constexpr int D_   = 64;
constexpr int NH   = 4;
constexpr int DH   = 16;
constexpr int M_   = 32;
constexpr int BS   = B_ * S_;          // 36864 tokens
constexpr int BSD  = BS * D_;          // 2359296
constexpr int BH   = B_ * NH;          // 8 sequences
constexpr int BHS  = BH * S_;          // 147456 rows
constexpr int BHSM = BHS * M_;         // 4718592
constexpr int CHUNK = 32;
constexpr int NC   = S_ / CHUNK;       // 576 chunks per sequence
constexpr int STATE = M_ * DH + M_;    // 544 floats of scan state
constexpr float DN = 0.5f;                         // 16^-0.25
constexpr float RATIO = 0.17677669529663687f;      // 32^-0.5

__device__ __forceinline__ unsigned short f2bf(float f) {
  bf16 h = __float2bfloat16(f);
  return *reinterpret_cast<unsigned short*>(&h);
}

// ---------------- fused: 1x1x1 conv3d + softplus + LayerNorm1 ----------------
__global__ void k_preln(const float* __restrict__ x, const float* __restrict__ pw,
                        const float* __restrict__ pb, const float* __restrict__ g,
                        const float* __restrict__ bb,
                        float* __restrict__ tok, float* __restrict__ h) {
  int token = blockIdx.x * 4 + (threadIdx.x >> 6);
  int lane = threadIdx.x & 63;
  int f = token * 64 + lane;          // flat over B*D*S
  int b = f / (D_ * S_);
  int r = f % (D_ * S_);
  int d = r / S_;
  int pos = r % S_;
  const float* xb = x + b * 3 * S_ + pos;
  float a = xb[0] * pw[d * 3 + 0] + xb[S_] * pw[d * 3 + 1] + xb[2 * S_] * pw[d * 3 + 2]
          + pb[d];
  float t = fmaxf(a, 0.f) + log1pf(expf(-fabsf(a)));  // softplus
  tok[f] = t;
  float s1 = t, s2 = t * t;
  for (int off = 32; off; off >>= 1) {
    s1 += __shfl_xor(s1, off);
    s2 += __shfl_xor(s2, off);
  }
  float mu = s1 * (1.f / 64.f);
  float var = s2 * (1.f / 64.f) - mu * mu;
  float rs = rsqrtf(var + 1e-5f);
  h[f] = (t - mu) * rs * g[lane] + bb[lane];
}

// ---------------- QKV projections via MFMA: 3 waves = {wq,wk,wv}, 32 tokens/block ----------------
__global__ void __launch_bounds__(192) k_qkv(const float* __restrict__ h,
                      const float* __restrict__ wq, const float* __restrict__ wk,
                      const float* __restrict__ wv,
                      float* __restrict__ q, float* __restrict__ k, float* __restrict__ v) {
  int tid = threadIdx.x;
  int w = tid >> 6;                 // wave -> matrix
  int L = tid & 63;
  int half = L >> 5;
  int n = L & 31;
  int tbase = blockIdx.x * 32;
  const float* wm = (w == 0) ? wq : (w == 1) ? wk : wv;
  float* outm = (w == 0) ? q : (w == 1) ? k : v;

  short8 a[4];
  {
    const float* hrow = h + (size_t)(tbase + n) * 64 + half * 8;
#pragma unroll
    for (int c = 0; c < 4; ++c) {
      float4 f0 = *(const float4*)&hrow[c * 16];
      float4 f1 = *(const float4*)&hrow[c * 16 + 4];
      a[c][0] = (short)f2bf(f0.x); a[c][1] = (short)f2bf(f0.y);
      a[c][2] = (short)f2bf(f0.z); a[c][3] = (short)f2bf(f0.w);
      a[c][4] = (short)f2bf(f1.x); a[c][5] = (short)f2bf(f1.y);
      a[c][6] = (short)f2bf(f1.z); a[c][7] = (short)f2bf(f1.w);
    }
  }
#pragma unroll
  for (int ct = 0; ct < 2; ++ct) {
    int col = ct * 32 + n;
    short8 bfrag[4];
#pragma unroll
    for (int c = 0; c < 4; ++c) {
#pragma unroll
      for (int j = 0; j < 8; ++j)
        bfrag[c][j] = (short)f2bf(wm[(c * 16 + half * 8 + j) * 64 + col]);
    }
    floatx16 acc;
#pragma unroll
    for (int i = 0; i < 16; ++i) acc[i] = 0.f;
    acc = __builtin_amdgcn_mfma_f32_32x32x16_bf16(a[0], bfrag[0], acc, 0, 0, 0);
    acc = __builtin_amdgcn_mfma_f32_32x32x16_bf16(a[1], bfrag[1], acc, 0, 0, 0);
    acc = __builtin_amdgcn_mfma_f32_32x32x16_bf16(a[2], bfrag[2], acc, 0, 0, 0);
    acc = __builtin_amdgcn_mfma_f32_32x32x16_bf16(a[3], bfrag[3], acc, 0, 0, 0);
    int head = col >> 4, di = col & 15;
#pragma unroll
    for (int r = 0; r < 16; ++r) {
      int row = (r & 3) + 8 * (r >> 2) + 4 * half;
      int token = tbase + row;
      int b = token / S_, s = token % S_;
      outm[((size_t)(b * NH + head) * S_ + s) * DH + di] = acc[r];
    }
  }
}

// ---------------- feature map via MFMA: dash = (q|k)*DN @ proj^T; 4 waves x 32 rows ----------------
// C-layout epilogue: per-row max (width-32 butterflies), dq via shfl, exp -> qpb (bf16);
// raw dash_k -> kp (fp32) + diagk; k block max -> part.
__global__ void __launch_bounds__(256) k_feat(const float* __restrict__ q,
                      const float* __restrict__ k, const float* __restrict__ proj,
                      bf16* __restrict__ qpb, float* __restrict__ kp,
                      float* __restrict__ diagk, float* __restrict__ part) {
  int tid = threadIdx.x;
  int w = tid >> 6;
  int L = tid & 63;
  int half = L >> 5;
  int n = L & 31;
  int rowbase = blockIdx.x * 128 + w * 32;

  float qv[8], kv[8];
  {
    const float* qrow = q + (size_t)(rowbase + n) * 16 + half * 8;
    const float* krow = k + (size_t)(rowbase + n) * 16 + half * 8;
    float4 q0 = *(const float4*)&qrow[0];
    float4 q1 = *(const float4*)&qrow[4];
    float4 k0 = *(const float4*)&krow[0];
    float4 k1 = *(const float4*)&krow[4];
    qv[0]=q0.x*DN; qv[1]=q0.y*DN; qv[2]=q0.z*DN; qv[3]=q0.w*DN;
    qv[4]=q1.x*DN; qv[5]=q1.y*DN; qv[6]=q1.z*DN; qv[7]=q1.w*DN;
    kv[0]=k0.x*DN; kv[1]=k0.y*DN; kv[2]=k0.z*DN; kv[3]=k0.w*DN;
    kv[4]=k1.x*DN; kv[5]=k1.y*DN; kv[6]=k1.z*DN; kv[7]=k1.w*DN;
  }
  short8 aq, ak, bp;
#pragma unroll
  for (int j = 0; j < 8; ++j) {
    aq[j] = (short)f2bf(qv[j]);
    ak[j] = (short)f2bf(kv[j]);
    bp[j] = (short)f2bf(proj[n * 16 + half * 8 + j]);   // B[d][m=n]
  }
  float dq = 0.f, dk = 0.f;
#pragma unroll
  for (int j = 0; j < 8; ++j) { dq += qv[j]*qv[j]; dk += kv[j]*kv[j]; }
  dq += __shfl_xor(dq, 32);
  dk += __shfl_xor(dk, 32);
  dq *= 0.5f; dk *= 0.5f;

  floatx16 Pq, Pk;
#pragma unroll
  for (int i = 0; i < 16; ++i) { Pq[i] = 0.f; Pk[i] = 0.f; }
  Pq = __builtin_amdgcn_mfma_f32_32x32x16_bf16(aq, bp, Pq, 0, 0, 0);
  Pk = __builtin_amdgcn_mfma_f32_32x32x16_bf16(ak, bp, Pk, 0, 0, 0);

  // raw dash_k out + diagk + block max
  float bmax = -3.4e38f;
#pragma unroll
  for (int r = 0; r < 16; ++r) {
    int i = (r & 3) + 8 * (r >> 2) + 4 * half;
    kp[(size_t)(rowbase + i) * 32 + n] = Pk[r];
    bmax = fmaxf(bmax, Pk[r]);
  }
  if (L < 32) diagk[rowbase + n] = dk;
  for (int off = 32; off; off >>= 1) bmax = fmaxf(bmax, __shfl_xor(bmax, off));
  if (L == 0) part[blockIdx.x * 4 + w] = bmax;

  // qp: per-row max over m (width-32 butterflies per reg), exp, bf16 out
#pragma unroll
  for (int r = 0; r < 16; ++r) {
    int i = (r & 3) + 8 * (r >> 2) + 4 * half;
    float mx = Pq[r];
    for (int off = 16; off; off >>= 1) mx = fmaxf(mx, __shfl_xor(mx, off, 32));
    float dqi = __shfl(dq, i, 64);          // row i's dq lives on lane i (<32)
    float val = RATIO * (expf(Pq[r] - dqi - mx) + 1e-4f);
    qpb[(size_t)(rowbase + i) * 32 + n] = __float2bfloat16(val);
  }
}

__global__ void k_maxred(const float* __restrict__ part, float* __restrict__ gmax) {
  float m = -3.4e38f;
  for (int i = threadIdx.x; i < BHS / 32; i += 256) m = fmaxf(m, part[i]);
  __shared__ float red[256];
  red[threadIdx.x] = m;
  __syncthreads();
  for (int s = 128; s; s >>= 1) {
    if (threadIdx.x < s) red[threadIdx.x] = fmaxf(red[threadIdx.x], red[threadIdx.x + s]);
    __syncthreads();
  }
  if (!threadIdx.x) gmax[0] = red[0];
}

// ---------------- kp-finalize (raw fp32 -> bf16 kpb) + per-chunk sums (LDS) ----------------
__global__ void __launch_bounds__(256) k_csfin(const float* __restrict__ diagk,
                      const float* __restrict__ gmax, const float* __restrict__ v,
                      const float* __restrict__ kp, bf16* __restrict__ kpb,
                      float* __restrict__ ckv) {
  __shared__ __align__(16) float sKp[CHUNK * 32];
  __shared__ __align__(16) float sVc[CHUNK * 16];
  int blk = blockIdx.x;
  int bh = blk / NC, c = blk % NC;
  int tid = threadIdx.x;
  int base = bh * S_ + c * CHUNK;
  float gm = gmax[0];
  {
    int row = tid >> 3, m4 = tid & 7;            // 32 rows x 8 float4
    float4 dash = *(const float4*)&kp[(size_t)(base + row) * 32 + m4 * 4];
    float dg = diagk[base + row] + gm;
    float4 fin;
    fin.x = RATIO * (expf(dash.x - dg) + 1e-4f);
    fin.y = RATIO * (expf(dash.y - dg) + 1e-4f);
    fin.z = RATIO * (expf(dash.z - dg) + 1e-4f);
    fin.w = RATIO * (expf(dash.w - dg) + 1e-4f);
    *(float4*)&sKp[row * 32 + m4 * 4] = fin;
    uint2 u;
    u.x = (unsigned)f2bf(fin.x) | ((unsigned)f2bf(fin.y) << 16);
    u.y = (unsigned)f2bf(fin.z) | ((unsigned)f2bf(fin.w) << 16);
    *(uint2*)&kpb[(size_t)(base + row) * 32 + m4 * 4] = u;
  }
  if (tid < 128) {                               // V: 32 rows x 4 float4
    int row = tid >> 2, c4 = tid & 3;
    *(float4*)&sVc[row * 16 + c4 * 4] = *(const float4*)&v[(size_t)(base + row) * 16 + c4 * 4];
  }
  __syncthreads();
  int m0 = tid >> 4, d0 = tid & 15;
  int m1 = m0 + 16;
  float a0 = 0.f, a1 = 0.f, az0 = 0.f, az1 = 0.f;
  for (int t = 0; t < CHUNK; ++t) {
    float k0 = sKp[t * 32 + m0];
    float k1 = sKp[t * 32 + m1];
    float vv = sVc[t * 16 + d0];
    a0 += k0 * vv;
    a1 += k1 * vv;
    if (d0 == 0) { az0 += k0; az1 += k1; }
  }
  float* outp = ckv + (size_t)blk * STATE;
  outp[m0 * 16 + d0] = a0;
  outp[m1 * 16 + d0] = a1;
  if (d0 == 0) { outp[512 + m0] = az0; outp[512 + m1] = az1; }
}

// ---------------- exclusive prefix over chunks (in place), one scan-column per thread ----------------
__global__ void k_prefix(float* __restrict__ ckv) {
  int idx = blockIdx.x * 256 + threadIdx.x;      // 17 blocks x 256 = 4352 = BH*544
  int bh = idx / STATE, c = idx % STATE;
  float run = 0.f;
  for (int j0 = 0; j0 < NC; j0 += 16) {
    float tb[16];
#pragma unroll
    for (int jj = 0; jj < 16; ++jj) tb[jj] = ckv[((size_t)bh * NC + j0 + jj) * STATE + c];
#pragma unroll
    for (int jj = 0; jj < 16; ++jj) {
      ckv[((size_t)bh * NC + j0 + jj) * STATE + c] = run;
      run += tb[jj];
    }
  }
}

// ---------------- within-chunk causal attention via MFMA (CHUNK=32; 4 chunks/block) ----------------
__global__ void __launch_bounds__(256) k_attn(const bf16* __restrict__ qpb,
                                              const bf16* __restrict__ kpb,
                                              const float* __restrict__ v,
                                              const float* __restrict__ ckv,
                                              float* __restrict__ attn) {
  __shared__ __align__(16) float sP[4][32 * 33 + 4];
  int tid = threadIdx.x;
  int w = tid >> 6;                 // wave -> chunk
  int L = tid & 63;
  int half = L >> 5;
  int n = L & 31;
  int chunk = blockIdx.x * 4 + w;
  int bh = chunk / NC, c = chunk % NC;
  int base = bh * S_ + c * CHUNK;

  short8 a1 = *(const short8*)(qpb + (size_t)(base + n) * 32 + half * 8);
  short8 a2 = *(const short8*)(qpb + (size_t)(base + n) * 32 + 16 + half * 8);
  short8 b1 = *(const short8*)(kpb + (size_t)(base + n) * 32 + half * 8);
  short8 b2 = *(const short8*)(kpb + (size_t)(base + n) * 32 + 16 + half * 8);

  floatx16 P;
#pragma unroll
  for (int i = 0; i < 16; ++i) P[i] = 0.f;
  P = __builtin_amdgcn_mfma_f32_32x32x16_bf16(a1, b1, P, 0, 0, 0);
  P = __builtin_amdgcn_mfma_f32_32x32x16_bf16(a2, b2, P, 0, 0, 0);

  float* sp = &sP[w][0];
#pragma unroll
  for (int r = 0; r < 16; ++r) {
    int i = (r & 3) + 8 * (r >> 2) + 4 * half;
    sp[i * 33 + n] = (n <= i) ? P[r] : 0.f;
  }
  __syncthreads();
  short8 pa1, pa2;
#pragma unroll
  for (int j = 0; j < 8; ++j) {
    pa1[j] = (short)f2bf(sp[n * 33 + half * 8 + j]);
    pa2[j] = (short)f2bf(sp[n * 33 + 16 + half * 8 + j]);
  }

  const float* cs = ckv + (size_t)chunk * STATE;
  short8 vb1, vb2, sb1, sb2;
#pragma unroll
  for (int j = 0; j < 8; ++j) {
    int t1 = half * 8 + j, t2 = 16 + half * 8 + j;
    float x1 = (n < 16) ? v[(size_t)(base + t1) * 16 + n] : (n == 16 ? 1.f : 0.f);
    float x2 = (n < 16) ? v[(size_t)(base + t2) * 16 + n] : (n == 16 ? 1.f : 0.f);
    vb1[j] = (short)f2bf(x1);
    vb2[j] = (short)f2bf(x2);
    float y1 = (n < 16) ? cs[t1 * 16 + n] : (n == 16 ? cs[512 + t1] : 0.f);
    float y2 = (n < 16) ? cs[t2 * 16 + n] : (n == 16 ? cs[512 + t2] : 0.f);
    sb1[j] = (short)f2bf(y1);
    sb2[j] = (short)f2bf(y2);
  }

  floatx16 O;
#pragma unroll
  for (int i = 0; i < 16; ++i) O[i] = 0.f;
  O = __builtin_amdgcn_mfma_f32_32x32x16_bf16(pa1, vb1, O, 0, 0, 0);
  O = __builtin_amdgcn_mfma_f32_32x32x16_bf16(pa2, vb2, O, 0, 0, 0);
  O = __builtin_amdgcn_mfma_f32_32x32x16_bf16(a1, sb1, O, 0, 0, 0);
  O = __builtin_amdgcn_mfma_f32_32x32x16_bf16(a2, sb2, O, 0, 0, 0);

  int srcl = 16 + 32 * half;
  float res[16];
#pragma unroll
  for (int r = 0; r < 16; ++r) {
    float den = __shfl(O[r], srcl, 64);
    res[r] = O[r] / den;
  }
  if (n < 16) {
    int b = bh >> 2, head = bh & 3;
#pragma unroll
    for (int r = 0; r < 16; ++r) {
      int i = (r & 3) + 8 * (r >> 2) + 4 * half;
      attn[((size_t)(b * S_ + c * CHUNK + i)) * 64 + head * 16 + n] = res[r];
    }
  }
}

// ---------------- attn @ wo + bo + residual + LayerNorm2 via MFMA ----------------
__global__ void __launch_bounds__(128) k_wo_ln(const float* __restrict__ attn,
                        const float* __restrict__ wo, const float* __restrict__ bo,
                        const float* __restrict__ tok, const float* __restrict__ g,
                        const float* __restrict__ bb,
                        float* __restrict__ tok2, float* __restrict__ h2) {
  __shared__ __align__(16) float sC[32 * 68];
  int tid = threadIdx.x;
  int w = tid >> 6;                 // coltile
  int L = tid & 63;
  int half = L >> 5;
  int n = L & 31;
  int tbase = blockIdx.x * 32;

  short8 a[4];
  {
    const float* arow = attn + (size_t)(tbase + n) * 64 + half * 8;
#pragma unroll
    for (int c = 0; c < 4; ++c) {
      float4 f0 = *(const float4*)&arow[c * 16];
      float4 f1 = *(const float4*)&arow[c * 16 + 4];
      a[c][0] = (short)f2bf(f0.x); a[c][1] = (short)f2bf(f0.y);
      a[c][2] = (short)f2bf(f0.z); a[c][3] = (short)f2bf(f0.w);
      a[c][4] = (short)f2bf(f1.x); a[c][5] = (short)f2bf(f1.y);
      a[c][6] = (short)f2bf(f1.z); a[c][7] = (short)f2bf(f1.w);
    }
  }
  int col = w * 32 + n;
  short8 bfrag[4];
#pragma unroll
  for (int c = 0; c < 4; ++c) {
#pragma unroll
    for (int j = 0; j < 8; ++j)
      bfrag[c][j] = (short)f2bf(wo[(c * 16 + half * 8 + j) * 64 + col]);
  }
  floatx16 acc;
#pragma unroll
  for (int i = 0; i < 16; ++i) acc[i] = 0.f;
  acc = __builtin_amdgcn_mfma_f32_32x32x16_bf16(a[0], bfrag[0], acc, 0, 0, 0);
  acc = __builtin_amdgcn_mfma_f32_32x32x16_bf16(a[1], bfrag[1], acc, 0, 0, 0);
  acc = __builtin_amdgcn_mfma_f32_32x32x16_bf16(a[2], bfrag[2], acc, 0, 0, 0);
  acc = __builtin_amdgcn_mfma_f32_32x32x16_bf16(a[3], bfrag[3], acc, 0, 0, 0);
  float bias = bo[col];
#pragma unroll
  for (int r = 0; r < 16; ++r) {
    int row = (r & 3) + 8 * (r >> 2) + 4 * half;
    sC[row * 68 + col] = acc[r] + tok[(size_t)(tbase + row) * 64 + col] + bias;
  }
  __syncthreads();
  int tg = tid >> 5, cg = tid & 31;
  int c0 = cg * 2, c1 = c0 + 1;
  float g0 = g[c0], g1 = g[c1], be0 = bb[c0], be1 = bb[c1];
#pragma unroll
  for (int i = 0; i < 8; ++i) {
    int lrow = tg * 8 + i;
    int token = tbase + lrow;
    float t0 = sC[lrow * 68 + c0];
    float t1 = sC[lrow * 68 + c1];
    float s1 = t0 + t1, s2 = t0 * t0 + t1 * t1;
    for (int off = 16; off; off >>= 1) {
      s1 += __shfl_xor(s1, off, 32);
      s2 += __shfl_xor(s2, off, 32);
    }
    float mu = s1 * (1.f / 64.f);
    float var = s2 * (1.f / 64.f) - mu * mu;
    float rs = rsqrtf(var + 1e-5f);
    tok2[token * 64 + c0] = t0;
    tok2[token * 64 + c1] = t1;
    h2[token * 64 + c0] = (t0 - mu) * rs * g0 + be0;
    h2[token * 64 + c1] = (t1 - mu) * rs * g1 + be1;
  }
}

// ---------------- FF1 + Gavg fused via MFMA ----------------
__global__ void __launch_bounds__(256) k_ffg(const float* __restrict__ h2,
                                             const float* __restrict__ w1,
                                             const float* __restrict__ b1,
                                             float* __restrict__ Gavg) {
  int tid = threadIdx.x;
  int w = tid >> 6;
  int L = tid & 63;
  int half = L >> 5;
  int n = L & 31;
  int blk = blockIdx.x;                 // B*64*9 = 1152
  int b = blk / 576;
  int rem = blk % 576;
  int ch = rem / 9;
  int jp0 = (rem % 9) * 4;
  int token_n = b * 18432 + ch * 288 + (n & 7) * 36 + jp0 + (n >> 3);

  short8 a[4];
  {
    const float* hrow = h2 + (size_t)token_n * 64 + half * 8;
#pragma unroll
    for (int c = 0; c < 4; ++c) {
      float4 f0 = *(const float4*)&hrow[c * 16];
      float4 f1 = *(const float4*)&hrow[c * 16 + 4];
      a[c][0] = (short)f2bf(f0.x); a[c][1] = (short)f2bf(f0.y);
      a[c][2] = (short)f2bf(f0.z); a[c][3] = (short)f2bf(f0.w);
      a[c][4] = (short)f2bf(f1.x); a[c][5] = (short)f2bf(f1.y);
      a[c][6] = (short)f2bf(f1.z); a[c][7] = (short)f2bf(f1.w);
    }
  }
  size_t gbase = ((size_t)(b * 64 + ch) * 36 + jp0);
#pragma unroll
  for (int ct = 0; ct < 2; ++ct) {
    int col = w * 64 + ct * 32 + n;
    short8 bfrag[4];
#pragma unroll
    for (int c = 0; c < 4; ++c) {
#pragma unroll
      for (int j = 0; j < 8; ++j)
        bfrag[c][j] = (short)f2bf(w1[(c * 16 + half * 8 + j) * 256 + col]);
    }
    floatx16 acc;
#pragma unroll
    for (int i = 0; i < 16; ++i) acc[i] = 0.f;
    acc = __builtin_amdgcn_mfma_f32_32x32x16_bf16(a[0], bfrag[0], acc, 0, 0, 0);
    acc = __builtin_amdgcn_mfma_f32_32x32x16_bf16(a[1], bfrag[1], acc, 0, 0, 0);
    acc = __builtin_amdgcn_mfma_f32_32x32x16_bf16(a[2], bfrag[2], acc, 0, 0, 0);
    acc = __builtin_amdgcn_mfma_f32_32x32x16_bf16(a[3], bfrag[3], acc, 0, 0, 0);
    float bias = b1[col];
#pragma unroll
    for (int j = 0; j < 4; ++j) {          // jp_local
      float s = 0.f;
#pragma unroll
      for (int rr = 0; rr < 4; ++rr) {
        float xg = acc[j * 4 + rr] + bias;
        s += 0.5f * xg * (1.f + erff(xg * 0.70710678118654752f));
      }
      s += __shfl_xor(s, 32);              // combine lane-halves (t 0..3 | 4..7)
      if (half == 0)
        Gavg[(gbase + j) * 256 + col] = s * 0.125f;
    }
  }
}

// ---------------- pool = mean_t(tok2) + Gavg @ W2 + b2 (FF2 folded 8x by linearity) ----------------
__global__ void __launch_bounds__(256) k_pool2(const float* __restrict__ Gavg,
                        const float* __restrict__ tok2, const float* __restrict__ w2,
                        const float* __restrict__ b2, float* __restrict__ pool) {
  __shared__ __align__(16) float sG[18 * 256];     // 18.4 KB
  __shared__ __align__(16) float sRed[4 * 18 * 64]; // 18.4 KB
  int blk = blockIdx.x;
  int b = blk / 128;
  int rem = blk % 128;
  int ch = rem >> 1, jph = rem & 1;
  int tid = threadIdx.x;
  size_t grow0 = ((size_t)(b * 64 + ch) * 36 + jph * 18) * 256;
  for (int e = tid; e < 1152; e += 256) {          // 18 rows x 64 float4
    int row = e >> 6, c4 = e & 63;
    *(float4*)&sG[row * 256 + c4 * 4] = *(const float4*)&Gavg[grow0 + row * 256 + c4 * 4];
  }
  __syncthreads();
  int kg = tid >> 6, dd = tid & 63;
  float acc[18];
#pragma unroll
  for (int i = 0; i < 18; ++i) acc[i] = 0.f;
  for (int k4 = 0; k4 < 16; ++k4) {
    int k = kg * 64 + k4 * 4;
    float w0 = w2[(k + 0) * 64 + dd];
    float w1 = w2[(k + 1) * 64 + dd];
    float w2v = w2[(k + 2) * 64 + dd];
    float w3 = w2[(k + 3) * 64 + dd];
#pragma unroll
    for (int i = 0; i < 18; ++i) {
      float4 gf = *(const float4*)&sG[i * 256 + k];   // wave-wide broadcast
      acc[i] += gf.x * w0 + gf.y * w1 + gf.z * w2v + gf.w * w3;
    }
  }
#pragma unroll
  for (int i = 0; i < 18; ++i) sRed[(kg * 18 + i) * 64 + dd] = acc[i];
  __syncthreads();
  for (int o = tid; o < 1152; o += 256) {
    int jp18 = o >> 6, d2 = o & 63;
    float gsum = sRed[(0 * 18 + jp18) * 64 + d2] + sRed[(1 * 18 + jp18) * 64 + d2]
               + sRed[(2 * 18 + jp18) * 64 + d2] + sRed[(3 * 18 + jp18) * 64 + d2];
    int p = (jph * 18 + jp18) * 64 + d2;
    size_t tbase = (size_t)b * 1179648 + (size_t)ch * 18432 + p;
    float ts = 0.f;
#pragma unroll
    for (int t = 0; t < 8; ++t) ts += tok2[tbase + t * 2304];
    pool[((size_t)(b * 64 + ch)) * HW + p] = ts * 0.125f + gsum + b2[d2];
  }
}

// ---------------- conv(5x5,pad2) + global-avg-pool folded ----------------
__global__ void __launch_bounds__(256) k_convsum(const float* __restrict__ pool,
                                                 const float* __restrict__ x,
                                                 const float* __restrict__ w,
                                                 float* __restrict__ partial) {
  int blk = blockIdx.x;          // b*65 + ch
  int b = blk / 65, ch = blk % 65;
  int tid = threadIdx.x;
  __shared__ float cls[25];
  __shared__ float red[256];
  if (tid < 25) {
    int ry = tid / 5, rx = tid % 5;
    int kh0 = (ry <= 2) ? 0 : (ry == 3 ? 1 : 2);
    int kh1 = (ry >= 2) ? 4 : (ry == 1 ? 3 : 2);
    int kw0 = (rx <= 2) ? 0 : (rx == 3 ? 1 : 2);
    int kw1 = (rx >= 2) ? 4 : (rx == 1 ? 3 : 2);
    float s = 0.f;
    for (int kh = kh0; kh <= kh1; ++kh)
      for (int kw = kw0; kw <= kw1; ++kw)
        s += w[ch * 25 + kh * 5 + kw];
    cls[tid] = s;
  }
  __syncthreads();
  const float* pc = (ch < 64) ? (pool + ((size_t)(b * 64 + ch)) * HW)
                              : (x + (size_t)b * 3 * S_ + 2 * S_);
  float acc = 0.f;
#pragma unroll
  for (int e = tid; e < HW; e += 256) {
    int iy = e / 48, ix = e % 48;
    int ry = (iy == 0) ? 0 : (iy == 1) ? 1 : (iy <= 45) ? 2 : (iy == 46) ? 3 : 4;
    int rx = (ix == 0) ? 0 : (ix == 1) ? 1 : (ix <= 45) ? 2 : (ix == 46) ? 3 : 4;
    acc += pc[e] * cls[ry * 5 + rx];
  }
  red[tid] = acc;
  __syncthreads();
  for (int s = 128; s; s >>= 1) {
    if (tid < s) red[tid] += red[tid + s];
    __syncthreads();
  }
  if (!tid) partial[blk] = red[0];
}

// ---------------- reduce 65 channel sums per b + readout ----------------
__global__ void k_final(const float* __restrict__ partial, const float* __restrict__ tgt_b,
                        const float* __restrict__ rd_w, const float* __restrict__ rd_b,
                        float* __restrict__ out) {
  int b = blockIdx.x;
  int lane = threadIdx.x;
  float s = (lane < 65) ? partial[b * 65 + lane] : 0.f;
  for (int off = 32; off; off >>= 1) s += __shfl_down(s, off, 64);
  __shared__ float r2;
  if (lane == 64) r2 = s;
  __syncthreads();
  if (!lane) {
    float tot = s + r2;
    float mean = tot / 2304.f + tgt_b[0];
    out[b] = mean * rd_w[0] + rd_b[0];
  }
}

extern "C" void kernel_launch(void* const* d_in, const int* in_sizes, int n_in,
                              void* d_out, int out_size, void* d_ws, size_t ws_size,
                              hipStream_t stream) {
  const float* x     = (const float*)d_in[0];
  const float* pre_w = (const float*)d_in[1];
  const float* pre_b = (const float*)d_in[2];
  const float* ln1_g = (const float*)d_in[3];
  const float* ln1_b = (const float*)d_in[4];
  const float* wq    = (const float*)d_in[5];
  const float* wk    = (const float*)d_in[6];
  const float* wv    = (const float*)d_in[7];
  const float* wo    = (const float*)d_in[8];
  const float* bo    = (const float*)d_in[9];
  const float* proj  = (const float*)d_in[10];
  const float* ln2_g = (const float*)d_in[11];
  const float* ln2_b = (const float*)d_in[12];
  const float* ff_w1 = (const float*)d_in[13];
  const float* ff_b1 = (const float*)d_in[14];
  const float* ff_w2 = (const float*)d_in[15];
  const float* ff_b2 = (const float*)d_in[16];
  const float* tgt_w = (const float*)d_in[17];
  const float* tgt_b = (const float*)d_in[18];
  const float* rd_w  = (const float*)d_in[19];
  const float* rd_b  = (const float*)d_in[20];
  float* out = (float*)d_out;

  float* ws = (float*)d_ws;
  // Round-13 layout: 0 tok | 1 v | 2 q -> Gavg+pool | 3 k/attnb | 4-5 kp (h first, h2 later)
  // | 6 qpb (bf16) | 7 kpb (bf16) | 8 ckv -> tok2 | smalls @ 9*BSD+147456
  float* tok   = ws;
  float* v     = ws + (size_t)BSD;
  float* q     = ws + 2 * (size_t)BSD;
  float* Gavg  = ws + 2 * (size_t)BSD;          // q dead after k_feat
  float* pool  = Gavg + 1179648;                // 294912 floats
  float* k     = ws + 3 * (size_t)BSD;
  float* h     = ws + 4 * (size_t)BSD;          // LN1 out; dead after k_qkv
  float* kp    = ws + 4 * (size_t)BSD;          // 2 BSD raw dash; dead after k_csfin
  bf16*  qpb   = (bf16*)(ws + 6 * (size_t)BSD); // BHSM bf16
  bf16*  kpb   = (bf16*)(ws + 7 * (size_t)BSD); // BHSM bf16
  float* ckv   = ws + 8 * (size_t)BSD;          // 2506752 floats; dead after k_attn
  float* tok2  = ws + 8 * (size_t)BSD;          // written by k_wo_ln (ckv dead)
  float* attnb = k;                             // k dead after k_feat
  float* h2    = ws + 4 * (size_t)BSD;          // kp dead after k_csfin
  float* smalls = ws + 9 * (size_t)BSD + 147456;
  float* diagk = smalls;                        // 147456
  float* part  = diagk + BHS;                   // 4608 used (18432 reserved)
  float* gmax  = part + BHSM / 256;             // 1
  float* partial = gmax + 64;                   // 130

  k_preln<<<dim3(BS / 4), dim3(256), 0, stream>>>(x, pre_w, pre_b, ln1_g, ln1_b, tok, h);
  k_qkv<<<dim3(BS / 32), dim3(192), 0, stream>>>(h, wq, wk, wv, q, k, v);
  k_feat<<<dim3(BHS / 128), dim3(256), 0, stream>>>(q, k, proj, qpb, kp, diagk, part);
  k_maxred<<<dim3(1), dim3(256), 0, stream>>>(part, gmax);
  k_csfin<<<dim3(BH * NC), dim3(256), 0, stream>>>(diagk, gmax, v, kp, kpb, ckv);
  k_prefix<<<dim3(BH * STATE / 256), dim3(256), 0, stream>>>(ckv);
  k_attn<<<dim3(BH * NC / 4), dim3(256), 0, stream>>>(qpb, kpb, v, ckv, attnb);
  k_wo_ln<<<dim3(BS / 32), dim3(128), 0, stream>>>(attnb, wo, bo, tok, ln2_g, ln2_b, tok2, h2);
  k_ffg<<<dim3(B_ * 64 * 9), dim3(256), 0, stream>>>(h2, ff_w1, ff_b1, Gavg);
  k_pool2<<<dim3(B_ * 64 * 2), dim3(256), 0, stream>>>(Gavg, tok2, ff_w2, ff_b2, pool);
  k_convsum<<<dim3(B_ * 65), dim3(256), 0, stream>>>(pool, x, tgt_w, partial);
  k_final<<<dim3(B_), dim3(128), 0, stream>>>(partial, tgt_b, rd_w, rd_b, out);
}

// Round 16
// 222.921 us; speedup vs baseline: 1.1828x; 1.0399x over previous
//
#include <hip/hip_runtime.h>
#include <hip/hip_bf16.h>
#include <math.h>

typedef __hip_bfloat16 bf16;
typedef __attribute__((ext_vector_type(8))) short short8;
typedef __attribute__((ext_vector_type(16))) float floatx16;

// Problem constants
constexpr int B_   = 2;
constexpr int T_   = 8;
constexpr int HW   = 48 * 48;          // 2304
constexpr int S_   = T_ * HW;          // 18432
constexpr int D_   = 64;
constexpr int NH   = 4;
constexpr int DH   = 16;
constexpr int M_   = 32;
constexpr int BS   = B_ * S_;          // 36864 tokens
constexpr int BSD  = BS * D_;          // 2359296
constexpr int BH   = B_ * NH;          // 8 sequences
constexpr int BHS  = BH * S_;          // 147456 rows
constexpr int BHSM = BHS * M_;         // 4718592
constexpr int CHUNK = 32;
constexpr int NC   = S_ / CHUNK;       // 576 chunks per sequence
constexpr int STATE = M_ * DH + M_;    // 544 floats of scan state
constexpr float DN = 0.5f;                         // 16^-0.25
constexpr float RATIO = 0.17677669529663687f;      // 32^-0.5

__device__ __forceinline__ unsigned short f2bf(float f) {
  bf16 h = __float2bfloat16(f);
  return *reinterpret_cast<unsigned short*>(&h);
}
__device__ __forceinline__ float bf2f(bf16 v) { return __bfloat162float(v); }

// ---------------- fused: 1x1x1 conv3d + softplus + LayerNorm1 (h out bf16) ----------------
__global__ void k_preln(const float* __restrict__ x, const float* __restrict__ pw,
                        const float* __restrict__ pb, const float* __restrict__ g,
                        const float* __restrict__ bb,
                        float* __restrict__ tok, bf16* __restrict__ h) {
  int token = blockIdx.x * 4 + (threadIdx.x >> 6);
  int lane = threadIdx.x & 63;
  int f = token * 64 + lane;          // flat over B*D*S
  int b = f / (D_ * S_);
  int r = f % (D_ * S_);
  int d = r / S_;
  int pos = r % S_;
  const float* xb = x + b * 3 * S_ + pos;
  float a = xb[0] * pw[d * 3 + 0] + xb[S_] * pw[d * 3 + 1] + xb[2 * S_] * pw[d * 3 + 2]
          + pb[d];
  float t = fmaxf(a, 0.f) + log1pf(expf(-fabsf(a)));  // softplus
  tok[f] = t;
  float s1 = t, s2 = t * t;
  for (int off = 32; off; off >>= 1) {
    s1 += __shfl_xor(s1, off);
    s2 += __shfl_xor(s2, off);
  }
  float mu = s1 * (1.f / 64.f);
  float var = s2 * (1.f / 64.f) - mu * mu;
  float rs = rsqrtf(var + 1e-5f);
  h[f] = __float2bfloat16((t - mu) * rs * g[lane] + bb[lane]);
}

// ---------------- QKV projections via MFMA: 3 waves = {wq,wk,wv}; q,k,v out bf16 ----------------
__global__ void __launch_bounds__(192) k_qkv(const bf16* __restrict__ h,
                      const float* __restrict__ wq, const float* __restrict__ wk,
                      const float* __restrict__ wv,
                      bf16* __restrict__ q, bf16* __restrict__ k, bf16* __restrict__ v) {
  int tid = threadIdx.x;
  int w = tid >> 6;                 // wave -> matrix
  int L = tid & 63;
  int half = L >> 5;
  int n = L & 31;
  int tbase = blockIdx.x * 32;
  const float* wm = (w == 0) ? wq : (w == 1) ? wk : wv;
  bf16* outm = (w == 0) ? q : (w == 1) ? k : v;

  short8 a[4];
  {
    const bf16* hrow = h + (size_t)(tbase + n) * 64 + half * 8;
#pragma unroll
    for (int c = 0; c < 4; ++c) a[c] = *(const short8*)(hrow + c * 16);
  }
#pragma unroll
  for (int ct = 0; ct < 2; ++ct) {
    int col = ct * 32 + n;
    short8 bfrag[4];
#pragma unroll
    for (int c = 0; c < 4; ++c) {
#pragma unroll
      for (int j = 0; j < 8; ++j)
        bfrag[c][j] = (short)f2bf(wm[(c * 16 + half * 8 + j) * 64 + col]);
    }
    floatx16 acc;
#pragma unroll
    for (int i = 0; i < 16; ++i) acc[i] = 0.f;
    acc = __builtin_amdgcn_mfma_f32_32x32x16_bf16(a[0], bfrag[0], acc, 0, 0, 0);
    acc = __builtin_amdgcn_mfma_f32_32x32x16_bf16(a[1], bfrag[1], acc, 0, 0, 0);
    acc = __builtin_amdgcn_mfma_f32_32x32x16_bf16(a[2], bfrag[2], acc, 0, 0, 0);
    acc = __builtin_amdgcn_mfma_f32_32x32x16_bf16(a[3], bfrag[3], acc, 0, 0, 0);
    int head = col >> 4, di = col & 15;
#pragma unroll
    for (int r = 0; r < 16; ++r) {
      int row = (r & 3) + 8 * (r >> 2) + 4 * half;
      int token = tbase + row;
      int b = token / S_, s = token % S_;
      outm[((size_t)(b * NH + head) * S_ + s) * DH + di] = __float2bfloat16(acc[r]);
    }
  }
}

// ---------------- feature map via MFMA (q,k bf16 in): qp bf16 + raw dash_k fp32 + diagk + max ----
__global__ void __launch_bounds__(256) k_feat(const bf16* __restrict__ q,
                      const bf16* __restrict__ k, const float* __restrict__ proj,
                      bf16* __restrict__ qpb, float* __restrict__ kp,
                      float* __restrict__ diagk, float* __restrict__ part) {
  int tid = threadIdx.x;
  int w = tid >> 6;
  int L = tid & 63;
  int half = L >> 5;
  int n = L & 31;
  int rowbase = blockIdx.x * 128 + w * 32;

  short8 qs = *(const short8*)(q + (size_t)(rowbase + n) * 16 + half * 8);
  short8 ks = *(const short8*)(k + (size_t)(rowbase + n) * 16 + half * 8);
  short8 aq, ak, bp;
  float dq = 0.f, dk = 0.f;
#pragma unroll
  for (int j = 0; j < 8; ++j) {
    float qf = __uint_as_float(((unsigned)(unsigned short)qs[j]) << 16) * DN;  // x0.5 exact
    float kf = __uint_as_float(((unsigned)(unsigned short)ks[j]) << 16) * DN;
    dq += qf * qf; dk += kf * kf;
    aq[j] = (short)f2bf(qf);
    ak[j] = (short)f2bf(kf);
    bp[j] = (short)f2bf(proj[n * 16 + half * 8 + j]);   // B[d][m=n]
  }
  dq += __shfl_xor(dq, 32);
  dk += __shfl_xor(dk, 32);
  dq *= 0.5f; dk *= 0.5f;

  floatx16 Pq, Pk;
#pragma unroll
  for (int i = 0; i < 16; ++i) { Pq[i] = 0.f; Pk[i] = 0.f; }
  Pq = __builtin_amdgcn_mfma_f32_32x32x16_bf16(aq, bp, Pq, 0, 0, 0);
  Pk = __builtin_amdgcn_mfma_f32_32x32x16_bf16(ak, bp, Pk, 0, 0, 0);

  float bmax = -3.4e38f;
#pragma unroll
  for (int r = 0; r < 16; ++r) {
    int i = (r & 3) + 8 * (r >> 2) + 4 * half;
    kp[(size_t)(rowbase + i) * 32 + n] = Pk[r];
    bmax = fmaxf(bmax, Pk[r]);
  }
  if (L < 32) diagk[rowbase + n] = dk;
  for (int off = 32; off; off >>= 1) bmax = fmaxf(bmax, __shfl_xor(bmax, off));
  if (L == 0) part[blockIdx.x * 4 + w] = bmax;

#pragma unroll
  for (int r = 0; r < 16; ++r) {
    int i = (r & 3) + 8 * (r >> 2) + 4 * half;
    float mx = Pq[r];
    for (int off = 16; off; off >>= 1) mx = fmaxf(mx, __shfl_xor(mx, off, 32));
    float dqi = __shfl(dq, i, 64);          // row i's dq lives on lane i (<32)
    float val = RATIO * (expf(Pq[r] - dqi - mx) + 1e-4f);
    qpb[(size_t)(rowbase + i) * 32 + n] = __float2bfloat16(val);
  }
}

__global__ void k_maxred(const float* __restrict__ part, float* __restrict__ gmax) {
  float m = -3.4e38f;
  for (int i = threadIdx.x; i < BHS / 32; i += 256) m = fmaxf(m, part[i]);
  __shared__ float red[256];
  red[threadIdx.x] = m;
  __syncthreads();
  for (int s = 128; s; s >>= 1) {
    if (threadIdx.x < s) red[threadIdx.x] = fmaxf(red[threadIdx.x], red[threadIdx.x + s]);
    __syncthreads();
  }
  if (!threadIdx.x) gmax[0] = red[0];
}

// ---------------- kp-finalize (raw fp32 -> bf16 kpb) + per-chunk sums (LDS); v bf16 ----------------
__global__ void __launch_bounds__(256) k_csfin(const float* __restrict__ diagk,
                      const float* __restrict__ gmax, const bf16* __restrict__ v,
                      const float* __restrict__ kp, bf16* __restrict__ kpb,
                      float* __restrict__ ckv) {
  __shared__ __align__(16) float sKp[CHUNK * 32];
  __shared__ __align__(16) float sVc[CHUNK * 16];
  int blk = blockIdx.x;
  int bh = blk / NC, c = blk % NC;
  int tid = threadIdx.x;
  int base = bh * S_ + c * CHUNK;
  float gm = gmax[0];
  {
    int row = tid >> 3, m4 = tid & 7;            // 32 rows x 8 float4
    float4 dash = *(const float4*)&kp[(size_t)(base + row) * 32 + m4 * 4];
    float dg = diagk[base + row] + gm;
    float4 fin;
    fin.x = RATIO * (expf(dash.x - dg) + 1e-4f);
    fin.y = RATIO * (expf(dash.y - dg) + 1e-4f);
    fin.z = RATIO * (expf(dash.z - dg) + 1e-4f);
    fin.w = RATIO * (expf(dash.w - dg) + 1e-4f);
    *(float4*)&sKp[row * 32 + m4 * 4] = fin;
    uint2 u;
    u.x = (unsigned)f2bf(fin.x) | ((unsigned)f2bf(fin.y) << 16);
    u.y = (unsigned)f2bf(fin.z) | ((unsigned)f2bf(fin.w) << 16);
    *(uint2*)&kpb[(size_t)(base + row) * 32 + m4 * 4] = u;
  }
  if (tid < 128) {                               // V: 32 rows x 4 groups of 4 bf16
    int row = tid >> 2, c4 = tid & 3;
    const bf16* vr = v + (size_t)(base + row) * 16 + c4 * 4;
    sVc[row * 16 + c4 * 4 + 0] = bf2f(vr[0]);
    sVc[row * 16 + c4 * 4 + 1] = bf2f(vr[1]);
    sVc[row * 16 + c4 * 4 + 2] = bf2f(vr[2]);
    sVc[row * 16 + c4 * 4 + 3] = bf2f(vr[3]);
  }
  __syncthreads();
  int m0 = tid >> 4, d0 = tid & 15;
  int m1 = m0 + 16;
  float a0 = 0.f, a1 = 0.f, az0 = 0.f, az1 = 0.f;
  for (int t = 0; t < CHUNK; ++t) {
    float k0 = sKp[t * 32 + m0];
    float k1 = sKp[t * 32 + m1];
    float vv = sVc[t * 16 + d0];
    a0 += k0 * vv;
    a1 += k1 * vv;
    if (d0 == 0) { az0 += k0; az1 += k1; }
  }
  float* outp = ckv + (size_t)blk * STATE;
  outp[m0 * 16 + d0] = a0;
  outp[m1 * 16 + d0] = a1;
  if (d0 == 0) { outp[512 + m0] = az0; outp[512 + m1] = az1; }
}

// ---------------- exclusive prefix over chunks (in place), one scan-column per thread ----------------
__global__ void k_prefix(float* __restrict__ ckv) {
  int idx = blockIdx.x * 256 + threadIdx.x;      // 17 blocks x 256 = 4352 = BH*544
  int bh = idx / STATE, c = idx % STATE;
  float run = 0.f;
  for (int j0 = 0; j0 < NC; j0 += 16) {
    float tb[16];
#pragma unroll
    for (int jj = 0; jj < 16; ++jj) tb[jj] = ckv[((size_t)bh * NC + j0 + jj) * STATE + c];
#pragma unroll
    for (int jj = 0; jj < 16; ++jj) {
      ckv[((size_t)bh * NC + j0 + jj) * STATE + c] = run;
      run += tb[jj];
    }
  }
}

// ---------------- within-chunk causal attention via MFMA (CHUNK=32; 4 chunks/block) ----------------
__global__ void __launch_bounds__(256) k_attn(const bf16* __restrict__ qpb,
                                              const bf16* __restrict__ kpb,
                                              const bf16* __restrict__ v,
                                              const float* __restrict__ ckv,
                                              bf16* __restrict__ attn) {
  __shared__ __align__(16) float sP[4][32 * 33 + 4];
  int tid = threadIdx.x;
  int w = tid >> 6;                 // wave -> chunk
  int L = tid & 63;
  int half = L >> 5;
  int n = L & 31;
  int chunk = blockIdx.x * 4 + w;
  int bh = chunk / NC, c = chunk % NC;
  int base = bh * S_ + c * CHUNK;

  short8 a1 = *(const short8*)(qpb + (size_t)(base + n) * 32 + half * 8);
  short8 a2 = *(const short8*)(qpb + (size_t)(base + n) * 32 + 16 + half * 8);
  short8 b1 = *(const short8*)(kpb + (size_t)(base + n) * 32 + half * 8);
  short8 b2 = *(const short8*)(kpb + (size_t)(base + n) * 32 + 16 + half * 8);

  floatx16 P;
#pragma unroll
  for (int i = 0; i < 16; ++i) P[i] = 0.f;
  P = __builtin_amdgcn_mfma_f32_32x32x16_bf16(a1, b1, P, 0, 0, 0);
  P = __builtin_amdgcn_mfma_f32_32x32x16_bf16(a2, b2, P, 0, 0, 0);

  float* sp = &sP[w][0];
#pragma unroll
  for (int r = 0; r < 16; ++r) {
    int i = (r & 3) + 8 * (r >> 2) + 4 * half;
    sp[i * 33 + n] = (n <= i) ? P[r] : 0.f;
  }
  __syncthreads();
  short8 pa1, pa2;
#pragma unroll
  for (int j = 0; j < 8; ++j) {
    pa1[j] = (short)f2bf(sp[n * 33 + half * 8 + j]);
    pa2[j] = (short)f2bf(sp[n * 33 + 16 + half * 8 + j]);
  }

  const float* cs = ckv + (size_t)chunk * STATE;
  const unsigned short one_bf = f2bf(1.f);
  short8 vb1, vb2, sb1, sb2;
#pragma unroll
  for (int j = 0; j < 8; ++j) {
    int t1 = half * 8 + j, t2 = 16 + half * 8 + j;
    vb1[j] = (n < 16) ? *(const short*)(v + (size_t)(base + t1) * 16 + n)
                      : (short)(n == 16 ? one_bf : 0);
    vb2[j] = (n < 16) ? *(const short*)(v + (size_t)(base + t2) * 16 + n)
                      : (short)(n == 16 ? one_bf : 0);
    float y1 = (n < 16) ? cs[t1 * 16 + n] : (n == 16 ? cs[512 + t1] : 0.f);
    float y2 = (n < 16) ? cs[t2 * 16 + n] : (n == 16 ? cs[512 + t2] : 0.f);
    sb1[j] = (short)f2bf(y1);
    sb2[j] = (short)f2bf(y2);
  }

  floatx16 O;
#pragma unroll
  for (int i = 0; i < 16; ++i) O[i] = 0.f;
  O = __builtin_amdgcn_mfma_f32_32x32x16_bf16(pa1, vb1, O, 0, 0, 0);
  O = __builtin_amdgcn_mfma_f32_32x32x16_bf16(pa2, vb2, O, 0, 0, 0);
  O = __builtin_amdgcn_mfma_f32_32x32x16_bf16(a1, sb1, O, 0, 0, 0);
  O = __builtin_amdgcn_mfma_f32_32x32x16_bf16(a2, sb2, O, 0, 0, 0);

  int srcl = 16 + 32 * half;
  float res[16];
#pragma unroll
  for (int r = 0; r < 16; ++r) {
    float den = __shfl(O[r], srcl, 64);
    res[r] = O[r] / den;
  }
  if (n < 16) {
    int b = bh >> 2, head = bh & 3;
#pragma unroll
    for (int r = 0; r < 16; ++r) {
      int i = (r & 3) + 8 * (r >> 2) + 4 * half;
      attn[((size_t)(b * S_ + c * CHUNK + i)) * 64 + head * 16 + n] = __float2bfloat16(res[r]);
    }
  }
}

// ---------------- attn(bf16) @ wo + bo + residual + LayerNorm2 via MFMA; h2 out bf16 ----------------
__global__ void __launch_bounds__(128) k_wo_ln(const bf16* __restrict__ attn,
                        const float* __restrict__ wo, const float* __restrict__ bo,
                        const float* __restrict__ tok, const float* __restrict__ g,
                        const float* __restrict__ bb,
                        float* __restrict__ tok2, bf16* __restrict__ h2) {
  __shared__ __align__(16) float sC[32 * 68];
  int tid = threadIdx.x;
  int w = tid >> 6;                 // coltile
  int L = tid & 63;
  int half = L >> 5;
  int n = L & 31;
  int tbase = blockIdx.x * 32;

  short8 a[4];
  {
    const bf16* arow = attn + (size_t)(tbase + n) * 64 + half * 8;
#pragma unroll
    for (int c = 0; c < 4; ++c) a[c] = *(const short8*)(arow + c * 16);
  }
  int col = w * 32 + n;
  short8 bfrag[4];
#pragma unroll
  for (int c = 0; c < 4; ++c) {
#pragma unroll
    for (int j = 0; j < 8; ++j)
      bfrag[c][j] = (short)f2bf(wo[(c * 16 + half * 8 + j) * 64 + col]);
  }
  floatx16 acc;
#pragma unroll
  for (int i = 0; i < 16; ++i) acc[i] = 0.f;
  acc = __builtin_amdgcn_mfma_f32_32x32x16_bf16(a[0], bfrag[0], acc, 0, 0, 0);
  acc = __builtin_amdgcn_mfma_f32_32x32x16_bf16(a[1], bfrag[1], acc, 0, 0, 0);
  acc = __builtin_amdgcn_mfma_f32_32x32x16_bf16(a[2], bfrag[2], acc, 0, 0, 0);
  acc = __builtin_amdgcn_mfma_f32_32x32x16_bf16(a[3], bfrag[3], acc, 0, 0, 0);
  float bias = bo[col];
#pragma unroll
  for (int r = 0; r < 16; ++r) {
    int row = (r & 3) + 8 * (r >> 2) + 4 * half;
    sC[row * 68 + col] = acc[r] + tok[(size_t)(tbase + row) * 64 + col] + bias;
  }
  __syncthreads();
  int tg = tid >> 5, cg = tid & 31;
  int c0 = cg * 2, c1 = c0 + 1;
  float g0 = g[c0], g1 = g[c1], be0 = bb[c0], be1 = bb[c1];
#pragma unroll
  for (int i = 0; i < 8; ++i) {
    int lrow = tg * 8 + i;
    int token = tbase + lrow;
    float t0 = sC[lrow * 68 + c0];
    float t1 = sC[lrow * 68 + c1];
    float s1 = t0 + t1, s2 = t0 * t0 + t1 * t1;
    for (int off = 16; off; off >>= 1) {
      s1 += __shfl_xor(s1, off, 32);
      s2 += __shfl_xor(s2, off, 32);
    }
    float mu = s1 * (1.f / 64.f);
    float var = s2 * (1.f / 64.f) - mu * mu;
    float rs = rsqrtf(var + 1e-5f);
    tok2[token * 64 + c0] = t0;
    tok2[token * 64 + c1] = t1;
    h2[token * 64 + c0] = __float2bfloat16((t0 - mu) * rs * g0 + be0);
    h2[token * 64 + c1] = __float2bfloat16((t1 - mu) * rs * g1 + be1);
  }
}

// ---------------- FF1 + Gavg fused via MFMA (h2 bf16 in) ----------------
__global__ void __launch_bounds__(256) k_ffg(const bf16* __restrict__ h2,
                                             const float* __restrict__ w1,
                                             const float* __restrict__ b1,
                                             float* __restrict__ Gavg) {
  int tid = threadIdx.x;
  int w = tid >> 6;
  int L = tid & 63;
  int half = L >> 5;
  int n = L & 31;
  int blk = blockIdx.x;                 // B*64*9 = 1152
  int b = blk / 576;
  int rem = blk % 576;
  int ch = rem / 9;
  int jp0 = (rem % 9) * 4;
  int token_n = b * 18432 + ch * 288 + (n & 7) * 36 + jp0 + (n >> 3);

  short8 a[4];
  {
    const bf16* hrow = h2 + (size_t)token_n * 64 + half * 8;
#pragma unroll
    for (int c = 0; c < 4; ++c) a[c] = *(const short8*)(hrow + c * 16);
  }
  size_t gbase = ((size_t)(b * 64 + ch) * 36 + jp0);
#pragma unroll
  for (int ct = 0; ct < 2; ++ct) {
    int col = w * 64 + ct * 32 + n;
    short8 bfrag[4];
#pragma unroll
    for (int c = 0; c < 4; ++c) {
#pragma unroll
      for (int j = 0; j < 8; ++j)
        bfrag[c][j] = (short)f2bf(w1[(c * 16 + half * 8 + j) * 256 + col]);
    }
    floatx16 acc;
#pragma unroll
    for (int i = 0; i < 16; ++i) acc[i] = 0.f;
    acc = __builtin_amdgcn_mfma_f32_32x32x16_bf16(a[0], bfrag[0], acc, 0, 0, 0);
    acc = __builtin_amdgcn_mfma_f32_32x32x16_bf16(a[1], bfrag[1], acc, 0, 0, 0);
    acc = __builtin_amdgcn_mfma_f32_32x32x16_bf16(a[2], bfrag[2], acc, 0, 0, 0);
    acc = __builtin_amdgcn_mfma_f32_32x32x16_bf16(a[3], bfrag[3], acc, 0, 0, 0);
    float bias = b1[col];
#pragma unroll
    for (int j = 0; j < 4; ++j) {          // jp_local
      float s = 0.f;
#pragma unroll
      for (int rr = 0; rr < 4; ++rr) {
        float xg = acc[j * 4 + rr] + bias;
        s += 0.5f * xg * (1.f + erff(xg * 0.70710678118654752f));
      }
      s += __shfl_xor(s, 32);              // combine lane-halves (t 0..3 | 4..7)
      if (half == 0)
        Gavg[(gbase + j) * 256 + col] = s * 0.125f;
    }
  }
}

// ---------------- pool = mean_t(tok2) + Gavg @ W2 + b2 (FF2 folded 8x by linearity) ----------------
__global__ void __launch_bounds__(256) k_pool2(const float* __restrict__ Gavg,
                        const float* __restrict__ tok2, const float* __restrict__ w2,
                        const float* __restrict__ b2, float* __restrict__ pool) {
  __shared__ __align__(16) float sG[18 * 256];     // 18.4 KB
  __shared__ __align__(16) float sRed[4 * 18 * 64]; // 18.4 KB
  int blk = blockIdx.x;
  int b = blk / 128;
  int rem = blk % 128;
  int ch = rem >> 1, jph = rem & 1;
  int tid = threadIdx.x;
  size_t grow0 = ((size_t)(b * 64 + ch) * 36 + jph * 18) * 256;
  for (int e = tid; e < 1152; e += 256) {          // 18 rows x 64 float4
    int row = e >> 6, c4 = e & 63;
    *(float4*)&sG[row * 256 + c4 * 4] = *(const float4*)&Gavg[grow0 + row * 256 + c4 * 4];
  }
  __syncthreads();
  int kg = tid >> 6, dd = tid & 63;
  float acc[18];
#pragma unroll
  for (int i = 0; i < 18; ++i) acc[i] = 0.f;
  for (int k4 = 0; k4 < 16; ++k4) {
    int k = kg * 64 + k4 * 4;
    float w0 = w2[(k + 0) * 64 + dd];
    float w1 = w2[(k + 1) * 64 + dd];
    float w2v = w2[(k + 2) * 64 + dd];
    float w3 = w2[(k + 3) * 64 + dd];
#pragma unroll
    for (int i = 0; i < 18; ++i) {
      float4 gf = *(const float4*)&sG[i * 256 + k];   // wave-wide broadcast
      acc[i] += gf.x * w0 + gf.y * w1 + gf.z * w2v + gf.w * w3;
    }
  }
#pragma unroll
  for (int i = 0; i < 18; ++i) sRed[(kg * 18 + i) * 64 + dd] = acc[i];
  __syncthreads();
  for (int o = tid; o < 1152; o += 256) {
    int jp18 = o >> 6, d2 = o & 63;
    float gsum = sRed[(0 * 18 + jp18) * 64 + d2] + sRed[(1 * 18 + jp18) * 64 + d2]
               + sRed[(2 * 18 + jp18) * 64 + d2] + sRed[(3 * 18 + jp18) * 64 + d2];
    int p = (jph * 18 + jp18) * 64 + d2;
    size_t tbase = (size_t)b * 1179648 + (size_t)ch * 18432 + p;
    float ts = 0.f;
#pragma unroll
    for (int t = 0; t < 8; ++t) ts += tok2[tbase + t * 2304];
    pool[((size_t)(b * 64 + ch)) * HW + p] = ts * 0.125f + gsum + b2[d2];
  }
}

// ---------------- conv(5x5,pad2) + global-avg-pool folded ----------------
__global__ void __launch_bounds__(256) k_convsum(const float* __restrict__ pool,
                                                 const float* __restrict__ x,
                                                 const float* __restrict__ w,
                                                 float* __restrict__ partial) {
  int blk = blockIdx.x;          // b*65 + ch
  int b = blk / 65, ch = blk % 65;
  int tid = threadIdx.x;
  __shared__ float cls[25];
  __shared__ float red[256];
  if (tid < 25) {
    int ry = tid / 5, rx = tid % 5;
    int kh0 = (ry <= 2) ? 0 : (ry == 3 ? 1 : 2);
    int kh1 = (ry >= 2) ? 4 : (ry == 1 ? 3 : 2);
    int kw0 = (rx <= 2) ? 0 : (rx == 3 ? 1 : 2);
    int kw1 = (rx >= 2) ? 4 : (rx == 1 ? 3 : 2);
    float s = 0.f;
    for (int kh = kh0; kh <= kh1; ++kh)
      for (int kw = kw0; kw <= kw1; ++kw)
        s += w[ch * 25 + kh * 5 + kw];
    cls[tid] = s;
  }
  __syncthreads();
  const float* pc = (ch < 64) ? (pool + ((size_t)(b * 64 + ch)) * HW)
                              : (x + (size_t)b * 3 * S_ + 2 * S_);
  float acc = 0.f;
#pragma unroll
  for (int e = tid; e < HW; e += 256) {
    int iy = e / 48, ix = e % 48;
    int ry = (iy == 0) ? 0 : (iy == 1) ? 1 : (iy <= 45) ? 2 : (iy == 46) ? 3 : 4;
    int rx = (ix == 0) ? 0 : (ix == 1) ? 1 : (ix <= 45) ? 2 : (ix == 46) ? 3 : 4;
    acc += pc[e] * cls[ry * 5 + rx];
  }
  red[tid] = acc;
  __syncthreads();
  for (int s = 128; s; s >>= 1) {
    if (tid < s) red[tid] += red[tid + s];
    __syncthreads();
  }
  if (!tid) partial[blk] = red[0];
}

// ---------------- reduce 65 channel sums per b + readout ----------------
__global__ void k_final(const float* __restrict__ partial, const float* __restrict__ tgt_b,
                        const float* __restrict__ rd_w, const float* __restrict__ rd_b,
                        float* __restrict__ out) {
  int b = blockIdx.x;
  int lane = threadIdx.x;
  float s = (lane < 65) ? partial[b * 65 + lane] : 0.f;
  for (int off = 32; off; off >>= 1) s += __shfl_down(s, off, 64);
  __shared__ float r2;
  if (lane == 64) r2 = s;
  __syncthreads();
  if (!lane) {
    float tot = s + r2;
    float mean = tot / 2304.f + tgt_b[0];
    out[b] = mean * rd_w[0] + rd_b[0];
  }
}

extern "C" void kernel_launch(void* const* d_in, const int* in_sizes, int n_in,
                              void* d_out, int out_size, void* d_ws, size_t ws_size,
                              hipStream_t stream) {
  const float* x     = (const float*)d_in[0];
  const float* pre_w = (const float*)d_in[1];
  const float* pre_b = (const float*)d_in[2];
  const float* ln1_g = (const float*)d_in[3];
  const float* ln1_b = (const float*)d_in[4];
  const float* wq    = (const float*)d_in[5];
  const float* wk    = (const float*)d_in[6];
  const float* wv    = (const float*)d_in[7];
  const float* wo    = (const float*)d_in[8];
  const float* bo    = (const float*)d_in[9];
  const float* proj  = (const float*)d_in[10];
  const float* ln2_g = (const float*)d_in[11];
  const float* ln2_b = (const float*)d_in[12];
  const float* ff_w1 = (const float*)d_in[13];
  const float* ff_b1 = (const float*)d_in[14];
  const float* ff_w2 = (const float*)d_in[15];
  const float* ff_b2 = (const float*)d_in[16];
  const float* tgt_w = (const float*)d_in[17];
  const float* tgt_b = (const float*)d_in[18];
  const float* rd_w  = (const float*)d_in[19];
  const float* rd_b  = (const float*)d_in[20];
  float* out = (float*)d_out;

  float* ws = (float*)d_ws;
  // 0 tok(f32) | 1 v(bf16, half) | 2 q(bf16 half) -> Gavg+pool | 3 k(bf16)/attnb(bf16)
  // 4-5 h(bf16 half) -> kp(f32 raw, 2 units) -> h2(bf16 half) | 6 qpb | 7 kpb
  // 8 ckv -> tok2 | smalls @ 9*BSD+147456
  float* tok   = ws;
  bf16*  v     = (bf16*)(ws + (size_t)BSD);
  bf16*  q     = (bf16*)(ws + 2 * (size_t)BSD);
  float* Gavg  = ws + 2 * (size_t)BSD;          // q dead after k_feat
  float* pool  = Gavg + 1179648;                // 294912 floats
  bf16*  k     = (bf16*)(ws + 3 * (size_t)BSD);
  bf16*  h     = (bf16*)(ws + 4 * (size_t)BSD); // LN1 out; dead after k_qkv
  float* kp    = ws + 4 * (size_t)BSD;          // 2 BSD raw dash; dead after k_csfin
  bf16*  qpb   = (bf16*)(ws + 6 * (size_t)BSD); // BHSM bf16
  bf16*  kpb   = (bf16*)(ws + 7 * (size_t)BSD); // BHSM bf16
  float* ckv   = ws + 8 * (size_t)BSD;          // 2506752 floats; dead after k_attn
  float* tok2  = ws + 8 * (size_t)BSD;          // written by k_wo_ln (ckv dead)
  bf16*  attnb = k;                             // k dead after k_feat
  bf16*  h2    = h;                             // kp dead after k_csfin
  float* smalls = ws + 9 * (size_t)BSD + 147456;
  float* diagk = smalls;                        // 147456
  float* part  = diagk + BHS;                   // 4608 used
  float* gmax  = part + BHSM / 256;             // 1
  float* partial = gmax + 64;                   // 130

  k_preln<<<dim3(BS / 4), dim3(256), 0, stream>>>(x, pre_w, pre_b, ln1_g, ln1_b, tok, h);
  k_qkv<<<dim3(BS / 32), dim3(192), 0, stream>>>(h, wq, wk, wv, q, k, v);
  k_feat<<<dim3(BHS / 128), dim3(256), 0, stream>>>(q, k, proj, qpb, kp, diagk, part);
  k_maxred<<<dim3(1), dim3(256), 0, stream>>>(part, gmax);
  k_csfin<<<dim3(BH * NC), dim3(256), 0, stream>>>(diagk, gmax, v, kp, kpb, ckv);
  k_prefix<<<dim3(BH * STATE / 256), dim3(256), 0, stream>>>(ckv);
  k_attn<<<dim3(BH * NC / 4), dim3(256), 0, stream>>>(qpb, kpb, v, ckv, attnb);
  k_wo_ln<<<dim3(BS / 32), dim3(128), 0, stream>>>(attnb, wo, bo, tok, ln2_g, ln2_b, tok2, h2);
  k_ffg<<<dim3(B_ * 64 * 9), dim3(256), 0, stream>>>(h2, ff_w1, ff_b1, Gavg);
  k_pool2<<<dim3(B_ * 64 * 2), dim3(256), 0, stream>>>(Gavg, tok2, ff_w2, ff_b2, pool);
  k_convsum<<<dim3(B_ * 65), dim3(256), 0, stream>>>(pool, x, tgt_w, partial);
  k_final<<<dim3(B_), dim3(128), 0, stream>>>(partial, tgt_b, rd_w, rd_b, out);
}

// Round 17
// 214.376 us; speedup vs baseline: 1.2300x; 1.0399x over previous
//
#include <hip/hip_runtime.h>
#include <hip/hip_bf16.h>
#include <math.h>

typedef __hip_bfloat16 bf16;
typedef __attribute__((ext_vector_type(8))) short short8;
typedef __attribute__((ext_vector_type(16))) float floatx16;

// Problem constants
constexpr int B_   = 2;
constexpr int T_   = 8;
constexpr int HW   = 48 * 48;          // 2304
constexpr int S_   = T_ * HW;          // 18432
constexpr int D_   = 64;
constexpr int NH   = 4;
constexpr int DH   = 16;
constexpr int M_   = 32;
constexpr int BS   = B_ * S_;          // 36864 tokens
constexpr int BSD  = BS * D_;          // 2359296
constexpr int BH   = B_ * NH;          // 8 sequences
constexpr int BHS  = BH * S_;          // 147456 rows
constexpr int BHSM = BHS * M_;         // 4718592
constexpr int CHUNK = 32;
constexpr int NC   = S_ / CHUNK;       // 576 chunks per sequence
constexpr int NSEG = 18;               // scan segments
constexpr int SEGLEN = 32;             // NC = NSEG * SEGLEN
constexpr int STATE = M_ * DH + M_;    // 544 floats of scan state
constexpr float DN = 0.5f;                         // 16^-0.25
constexpr float RATIO = 0.17677669529663687f;      // 32^-0.5

__device__ __forceinline__ unsigned short f2bf(float f) {
  bf16 h = __float2bfloat16(f);
  return *reinterpret_cast<unsigned short*>(&h);
}
__device__ __forceinline__ float bf2f(bf16 v) { return __bfloat162float(v); }

// ---------------- fused: 1x1x1 conv3d + softplus + LayerNorm1 (tok, h out bf16) ----------------
__global__ void k_preln(const float* __restrict__ x, const float* __restrict__ pw,
                        const float* __restrict__ pb, const float* __restrict__ g,
                        const float* __restrict__ bb,
                        bf16* __restrict__ tok, bf16* __restrict__ h) {
  int token = blockIdx.x * 4 + (threadIdx.x >> 6);
  int lane = threadIdx.x & 63;
  int f = token * 64 + lane;          // flat over B*D*S
  int b = f / (D_ * S_);
  int r = f % (D_ * S_);
  int d = r / S_;
  int pos = r % S_;
  const float* xb = x + b * 3 * S_ + pos;
  float a = xb[0] * pw[d * 3 + 0] + xb[S_] * pw[d * 3 + 1] + xb[2 * S_] * pw[d * 3 + 2]
          + pb[d];
  float t = fmaxf(a, 0.f) + log1pf(expf(-fabsf(a)));  // softplus
  tok[f] = __float2bfloat16(t);
  float s1 = t, s2 = t * t;
  for (int off = 32; off; off >>= 1) {
    s1 += __shfl_xor(s1, off);
    s2 += __shfl_xor(s2, off);
  }
  float mu = s1 * (1.f / 64.f);
  float var = s2 * (1.f / 64.f) - mu * mu;
  float rs = rsqrtf(var + 1e-5f);
  h[f] = __float2bfloat16((t - mu) * rs * g[lane] + bb[lane]);
}

// ---------------- QKV projections via MFMA: 3 waves = {wq,wk,wv}; q,k,v out bf16 ----------------
__global__ void __launch_bounds__(192) k_qkv(const bf16* __restrict__ h,
                      const float* __restrict__ wq, const float* __restrict__ wk,
                      const float* __restrict__ wv,
                      bf16* __restrict__ q, bf16* __restrict__ k, bf16* __restrict__ v) {
  int tid = threadIdx.x;
  int w = tid >> 6;                 // wave -> matrix
  int L = tid & 63;
  int half = L >> 5;
  int n = L & 31;
  int tbase = blockIdx.x * 32;
  const float* wm = (w == 0) ? wq : (w == 1) ? wk : wv;
  bf16* outm = (w == 0) ? q : (w == 1) ? k : v;

  short8 a[4];
  {
    const bf16* hrow = h + (size_t)(tbase + n) * 64 + half * 8;
#pragma unroll
    for (int c = 0; c < 4; ++c) a[c] = *(const short8*)(hrow + c * 16);
  }
#pragma unroll
  for (int ct = 0; ct < 2; ++ct) {
    int col = ct * 32 + n;
    short8 bfrag[4];
#pragma unroll
    for (int c = 0; c < 4; ++c) {
#pragma unroll
      for (int j = 0; j < 8; ++j)
        bfrag[c][j] = (short)f2bf(wm[(c * 16 + half * 8 + j) * 64 + col]);
    }
    floatx16 acc;
#pragma unroll
    for (int i = 0; i < 16; ++i) acc[i] = 0.f;
    acc = __builtin_amdgcn_mfma_f32_32x32x16_bf16(a[0], bfrag[0], acc, 0, 0, 0);
    acc = __builtin_amdgcn_mfma_f32_32x32x16_bf16(a[1], bfrag[1], acc, 0, 0, 0);
    acc = __builtin_amdgcn_mfma_f32_32x32x16_bf16(a[2], bfrag[2], acc, 0, 0, 0);
    acc = __builtin_amdgcn_mfma_f32_32x32x16_bf16(a[3], bfrag[3], acc, 0, 0, 0);
    int head = col >> 4, di = col & 15;
#pragma unroll
    for (int r = 0; r < 16; ++r) {
      int row = (r & 3) + 8 * (r >> 2) + 4 * half;
      int token = tbase + row;
      int b = token / S_, s = token % S_;
      outm[((size_t)(b * NH + head) * S_ + s) * DH + di] = __float2bfloat16(acc[r]);
    }
  }
}

// ---------------- feature map via MFMA (q,k bf16 in): qp bf16 + raw dash_k fp32 + diagk + max ----
__global__ void __launch_bounds__(256) k_feat(const bf16* __restrict__ q,
                      const bf16* __restrict__ k, const float* __restrict__ proj,
                      bf16* __restrict__ qpb, float* __restrict__ kp,
                      float* __restrict__ diagk, float* __restrict__ part) {
  int tid = threadIdx.x;
  int w = tid >> 6;
  int L = tid & 63;
  int half = L >> 5;
  int n = L & 31;
  int rowbase = blockIdx.x * 128 + w * 32;

  short8 qs = *(const short8*)(q + (size_t)(rowbase + n) * 16 + half * 8);
  short8 ks = *(const short8*)(k + (size_t)(rowbase + n) * 16 + half * 8);
  short8 aq, ak, bp;
  float dq = 0.f, dk = 0.f;
#pragma unroll
  for (int j = 0; j < 8; ++j) {
    float qf = __uint_as_float(((unsigned)(unsigned short)qs[j]) << 16) * DN;  // x0.5 exact
    float kf = __uint_as_float(((unsigned)(unsigned short)ks[j]) << 16) * DN;
    dq += qf * qf; dk += kf * kf;
    aq[j] = (short)f2bf(qf);
    ak[j] = (short)f2bf(kf);
    bp[j] = (short)f2bf(proj[n * 16 + half * 8 + j]);   // B[d][m=n]
  }
  dq += __shfl_xor(dq, 32);
  dk += __shfl_xor(dk, 32);
  dq *= 0.5f; dk *= 0.5f;

  floatx16 Pq, Pk;
#pragma unroll
  for (int i = 0; i < 16; ++i) { Pq[i] = 0.f; Pk[i] = 0.f; }
  Pq = __builtin_amdgcn_mfma_f32_32x32x16_bf16(aq, bp, Pq, 0, 0, 0);
  Pk = __builtin_amdgcn_mfma_f32_32x32x16_bf16(ak, bp, Pk, 0, 0, 0);

  float bmax = -3.4e38f;
#pragma unroll
  for (int r = 0; r < 16; ++r) {
    int i = (r & 3) + 8 * (r >> 2) + 4 * half;
    kp[(size_t)(rowbase + i) * 32 + n] = Pk[r];
    bmax = fmaxf(bmax, Pk[r]);
  }
  if (L < 32) diagk[rowbase + n] = dk;
  for (int off = 32; off; off >>= 1) bmax = fmaxf(bmax, __shfl_xor(bmax, off));
  if (L == 0) part[blockIdx.x * 4 + w] = bmax;

#pragma unroll
  for (int r = 0; r < 16; ++r) {
    int i = (r & 3) + 8 * (r >> 2) + 4 * half;
    float mx = Pq[r];
    for (int off = 16; off; off >>= 1) mx = fmaxf(mx, __shfl_xor(mx, off, 32));
    float dqi = __shfl(dq, i, 64);          // row i's dq lives on lane i (<32)
    float val = RATIO * (expf(Pq[r] - dqi - mx) + 1e-4f);
    qpb[(size_t)(rowbase + i) * 32 + n] = __float2bfloat16(val);
  }
}

__global__ void k_maxred(const float* __restrict__ part, float* __restrict__ gmax) {
  float m = -3.4e38f;
  for (int i = threadIdx.x; i < BHS / 32; i += 256) m = fmaxf(m, part[i]);
  __shared__ float red[256];
  red[threadIdx.x] = m;
  __syncthreads();
  for (int s = 128; s; s >>= 1) {
    if (threadIdx.x < s) red[threadIdx.x] = fmaxf(red[threadIdx.x], red[threadIdx.x + s]);
    __syncthreads();
  }
  if (!threadIdx.x) gmax[0] = red[0];
}

// ---------------- kp-finalize (raw fp32 -> bf16 kpb) + per-chunk sums (LDS); v bf16 ----------------
__global__ void __launch_bounds__(256) k_csfin(const float* __restrict__ diagk,
                      const float* __restrict__ gmax, const bf16* __restrict__ v,
                      const float* __restrict__ kp, bf16* __restrict__ kpb,
                      float* __restrict__ ckv) {
  __shared__ __align__(16) float sKp[CHUNK * 32];
  __shared__ __align__(16) float sVc[CHUNK * 16];
  int blk = blockIdx.x;
  int bh = blk / NC, c = blk % NC;
  int tid = threadIdx.x;
  int base = bh * S_ + c * CHUNK;
  float gm = gmax[0];
  {
    int row = tid >> 3, m4 = tid & 7;            // 32 rows x 8 float4
    float4 dash = *(const float4*)&kp[(size_t)(base + row) * 32 + m4 * 4];
    float dg = diagk[base + row] + gm;
    float4 fin;
    fin.x = RATIO * (expf(dash.x - dg) + 1e-4f);
    fin.y = RATIO * (expf(dash.y - dg) + 1e-4f);
    fin.z = RATIO * (expf(dash.z - dg) + 1e-4f);
    fin.w = RATIO * (expf(dash.w - dg) + 1e-4f);
    *(float4*)&sKp[row * 32 + m4 * 4] = fin;
    uint2 u;
    u.x = (unsigned)f2bf(fin.x) | ((unsigned)f2bf(fin.y) << 16);
    u.y = (unsigned)f2bf(fin.z) | ((unsigned)f2bf(fin.w) << 16);
    *(uint2*)&kpb[(size_t)(base + row) * 32 + m4 * 4] = u;
  }
  if (tid < 128) {                               // V: 32 rows x 4 groups of 4 bf16
    int row = tid >> 2, c4 = tid & 3;
    const bf16* vr = v + (size_t)(base + row) * 16 + c4 * 4;
    sVc[row * 16 + c4 * 4 + 0] = bf2f(vr[0]);
    sVc[row * 16 + c4 * 4 + 1] = bf2f(vr[1]);
    sVc[row * 16 + c4 * 4 + 2] = bf2f(vr[2]);
    sVc[row * 16 + c4 * 4 + 3] = bf2f(vr[3]);
  }
  __syncthreads();
  int m0 = tid >> 4, d0 = tid & 15;
  int m1 = m0 + 16;
  float a0 = 0.f, a1 = 0.f, az0 = 0.f, az1 = 0.f;
  for (int t = 0; t < CHUNK; ++t) {
    float k0 = sKp[t * 32 + m0];
    float k1 = sKp[t * 32 + m1];
    float vv = sVc[t * 16 + d0];
    a0 += k0 * vv;
    a1 += k1 * vv;
    if (d0 == 0) { az0 += k0; az1 += k1; }
  }
  float* outp = ckv + (size_t)blk * STATE;
  outp[m0 * 16 + d0] = a0;
  outp[m1 * 16 + d0] = a1;
  if (d0 == 0) { outp[512 + m0] = az0; outp[512 + m1] = az1; }
}

// ---------------- 3-phase segmented exclusive scan over chunks ----------------
// Phase 1: per-(bh,seg,c) segment sum. grid 306 x 256 = BH*NSEG*STATE threads.
__global__ void k_scan1(const float* __restrict__ ckv, float* __restrict__ segsum) {
  int idx = blockIdx.x * 256 + threadIdx.x;
  int c = idx % STATE;
  int rem = idx / STATE;
  int seg = rem % NSEG;
  int bh = rem / NSEG;
  size_t base = ((size_t)bh * NC + seg * SEGLEN) * STATE + c;
  float s = 0.f;
#pragma unroll 8
  for (int i = 0; i < SEGLEN; ++i) s += ckv[base + (size_t)i * STATE];
  segsum[idx] = s;
}

// Phase 2: exclusive scan of NSEG segment totals per (bh,c). grid 17 x 256.
__global__ void k_scan2(float* __restrict__ segsum) {
  int idx = blockIdx.x * 256 + threadIdx.x;      // BH*STATE = 4352
  int c = idx % STATE;
  int bh = idx / STATE;
  float tb[NSEG];
#pragma unroll
  for (int s = 0; s < NSEG; ++s)
    tb[s] = segsum[((size_t)bh * NSEG + s) * STATE + c];
  float run = 0.f;
#pragma unroll
  for (int s = 0; s < NSEG; ++s) {
    segsum[((size_t)bh * NSEG + s) * STATE + c] = run;
    run += tb[s];
  }
}

// Phase 3: local exclusive scan + segment offset, in place. grid 306 x 256.
__global__ void k_scan3(float* __restrict__ ckv, const float* __restrict__ segsum) {
  int idx = blockIdx.x * 256 + threadIdx.x;
  int c = idx % STATE;
  int rem = idx / STATE;
  int seg = rem % NSEG;
  int bh = rem / NSEG;
  float run = segsum[idx];
  size_t base = ((size_t)bh * NC + seg * SEGLEN) * STATE + c;
  for (int i0 = 0; i0 < SEGLEN; i0 += 8) {
    float tb[8];
#pragma unroll
    for (int j = 0; j < 8; ++j) tb[j] = ckv[base + (size_t)(i0 + j) * STATE];
#pragma unroll
    for (int j = 0; j < 8; ++j) {
      ckv[base + (size_t)(i0 + j) * STATE] = run;
      run += tb[j];
    }
  }
}

// ---------------- within-chunk causal attention via MFMA (CHUNK=32; 4 chunks/block) ----------------
__global__ void __launch_bounds__(256) k_attn(const bf16* __restrict__ qpb,
                                              const bf16* __restrict__ kpb,
                                              const bf16* __restrict__ v,
                                              const float* __restrict__ ckv,
                                              bf16* __restrict__ attn) {
  __shared__ __align__(16) float sP[4][32 * 33 + 4];
  int tid = threadIdx.x;
  int w = tid >> 6;                 // wave -> chunk
  int L = tid & 63;
  int half = L >> 5;
  int n = L & 31;
  int chunk = blockIdx.x * 4 + w;
  int bh = chunk / NC, c = chunk % NC;
  int base = bh * S_ + c * CHUNK;

  short8 a1 = *(const short8*)(qpb + (size_t)(base + n) * 32 + half * 8);
  short8 a2 = *(const short8*)(qpb + (size_t)(base + n) * 32 + 16 + half * 8);
  short8 b1 = *(const short8*)(kpb + (size_t)(base + n) * 32 + half * 8);
  short8 b2 = *(const short8*)(kpb + (size_t)(base + n) * 32 + 16 + half * 8);

  floatx16 P;
#pragma unroll
  for (int i = 0; i < 16; ++i) P[i] = 0.f;
  P = __builtin_amdgcn_mfma_f32_32x32x16_bf16(a1, b1, P, 0, 0, 0);
  P = __builtin_amdgcn_mfma_f32_32x32x16_bf16(a2, b2, P, 0, 0, 0);

  float* sp = &sP[w][0];
#pragma unroll
  for (int r = 0; r < 16; ++r) {
    int i = (r & 3) + 8 * (r >> 2) + 4 * half;
    sp[i * 33 + n] = (n <= i) ? P[r] : 0.f;
  }
  __syncthreads();
  short8 pa1, pa2;
#pragma unroll
  for (int j = 0; j < 8; ++j) {
    pa1[j] = (short)f2bf(sp[n * 33 + half * 8 + j]);
    pa2[j] = (short)f2bf(sp[n * 33 + 16 + half * 8 + j]);
  }

  const float* cs = ckv + (size_t)chunk * STATE;
  const unsigned short one_bf = f2bf(1.f);
  short8 vb1, vb2, sb1, sb2;
#pragma unroll
  for (int j = 0; j < 8; ++j) {
    int t1 = half * 8 + j, t2 = 16 + half * 8 + j;
    vb1[j] = (n < 16) ? *(const short*)(v + (size_t)(base + t1) * 16 + n)
                      : (short)(n == 16 ? one_bf : 0);
    vb2[j] = (n < 16) ? *(const short*)(v + (size_t)(base + t2) * 16 + n)
                      : (short)(n == 16 ? one_bf : 0);
    float y1 = (n < 16) ? cs[t1 * 16 + n] : (n == 16 ? cs[512 + t1] : 0.f);
    float y2 = (n < 16) ? cs[t2 * 16 + n] : (n == 16 ? cs[512 + t2] : 0.f);
    sb1[j] = (short)f2bf(y1);
    sb2[j] = (short)f2bf(y2);
  }

  floatx16 O;
#pragma unroll
  for (int i = 0; i < 16; ++i) O[i] = 0.f;
  O = __builtin_amdgcn_mfma_f32_32x32x16_bf16(pa1, vb1, O, 0, 0, 0);
  O = __builtin_amdgcn_mfma_f32_32x32x16_bf16(pa2, vb2, O, 0, 0, 0);
  O = __builtin_amdgcn_mfma_f32_32x32x16_bf16(a1, sb1, O, 0, 0, 0);
  O = __builtin_amdgcn_mfma_f32_32x32x16_bf16(a2, sb2, O, 0, 0, 0);

  int srcl = 16 + 32 * half;
  float res[16];
#pragma unroll
  for (int r = 0; r < 16; ++r) {
    float den = __shfl(O[r], srcl, 64);
    res[r] = O[r] / den;
  }
  if (n < 16) {
    int b = bh >> 2, head = bh & 3;
#pragma unroll
    for (int r = 0; r < 16; ++r) {
      int i = (r & 3) + 8 * (r >> 2) + 4 * half;
      attn[((size_t)(b * S_ + c * CHUNK + i)) * 64 + head * 16 + n] = __float2bfloat16(res[r]);
    }
  }
}

// ---------------- attn(bf16) @ wo + bo + residual(bf16) + LayerNorm2; tok2 bf16, h2 bf16 ----------
__global__ void __launch_bounds__(128) k_wo_ln(const bf16* __restrict__ attn,
                        const float* __restrict__ wo, const float* __restrict__ bo,
                        const bf16* __restrict__ tok, const float* __restrict__ g,
                        const float* __restrict__ bb,
                        bf16* __restrict__ tok2, bf16* __restrict__ h2) {
  __shared__ __align__(16) float sC[32 * 68];
  int tid = threadIdx.x;
  int w = tid >> 6;                 // coltile
  int L = tid & 63;
  int half = L >> 5;
  int n = L & 31;
  int tbase = blockIdx.x * 32;

  short8 a[4];
  {
    const bf16* arow = attn + (size_t)(tbase + n) * 64 + half * 8;
#pragma unroll
    for (int c = 0; c < 4; ++c) a[c] = *(const short8*)(arow + c * 16);
  }
  int col = w * 32 + n;
  short8 bfrag[4];
#pragma unroll
  for (int c = 0; c < 4; ++c) {
#pragma unroll
    for (int j = 0; j < 8; ++j)
      bfrag[c][j] = (short)f2bf(wo[(c * 16 + half * 8 + j) * 64 + col]);
  }
  floatx16 acc;
#pragma unroll
  for (int i = 0; i < 16; ++i) acc[i] = 0.f;
  acc = __builtin_amdgcn_mfma_f32_32x32x16_bf16(a[0], bfrag[0], acc, 0, 0, 0);
  acc = __builtin_amdgcn_mfma_f32_32x32x16_bf16(a[1], bfrag[1], acc, 0, 0, 0);
  acc = __builtin_amdgcn_mfma_f32_32x32x16_bf16(a[2], bfrag[2], acc, 0, 0, 0);
  acc = __builtin_amdgcn_mfma_f32_32x32x16_bf16(a[3], bfrag[3], acc, 0, 0, 0);
  float bias = bo[col];
#pragma unroll
  for (int r = 0; r < 16; ++r) {
    int row = (r & 3) + 8 * (r >> 2) + 4 * half;
    sC[row * 68 + col] = acc[r] + bf2f(tok[(size_t)(tbase + row) * 64 + col]) + bias;
  }
  __syncthreads();
  int tg = tid >> 5, cg = tid & 31;
  int c0 = cg * 2, c1 = c0 + 1;
  float g0 = g[c0], g1 = g[c1], be0 = bb[c0], be1 = bb[c1];
#pragma unroll
  for (int i = 0; i < 8; ++i) {
    int lrow = tg * 8 + i;
    int token = tbase + lrow;
    float t0 = sC[lrow * 68 + c0];
    float t1 = sC[lrow * 68 + c1];
    float s1 = t0 + t1, s2 = t0 * t0 + t1 * t1;
    for (int off = 16; off; off >>= 1) {
      s1 += __shfl_xor(s1, off, 32);
      s2 += __shfl_xor(s2, off, 32);
    }
    float mu = s1 * (1.f / 64.f);
    float var = s2 * (1.f / 64.f) - mu * mu;
    float rs = rsqrtf(var + 1e-5f);
    tok2[token * 64 + c0] = __float2bfloat16(t0);
    tok2[token * 64 + c1] = __float2bfloat16(t1);
    h2[token * 64 + c0] = __float2bfloat16((t0 - mu) * rs * g0 + be0);
    h2[token * 64 + c1] = __float2bfloat16((t1 - mu) * rs * g1 + be1);
  }
}

// ---------------- FF1 + Gavg fused via MFMA (h2 bf16 in) ----------------
__global__ void __launch_bounds__(256) k_ffg(const bf16* __restrict__ h2,
                                             const float* __restrict__ w1,
                                             const float* __restrict__ b1,
                                             float* __restrict__ Gavg) {
  int tid = threadIdx.x;
  int w = tid >> 6;
  int L = tid & 63;
  int half = L >> 5;
  int n = L & 31;
  int blk = blockIdx.x;                 // B*64*9 = 1152
  int b = blk / 576;
  int rem = blk % 576;
  int ch = rem / 9;
  int jp0 = (rem % 9) * 4;
  int token_n = b * 18432 + ch * 288 + (n & 7) * 36 + jp0 + (n >> 3);

  short8 a[4];
  {
    const bf16* hrow = h2 + (size_t)token_n * 64 + half * 8;
#pragma unroll
    for (int c = 0; c < 4; ++c) a[c] = *(const short8*)(hrow + c * 16);
  }
  size_t gbase = ((size_t)(b * 64 + ch) * 36 + jp0);
#pragma unroll
  for (int ct = 0; ct < 2; ++ct) {
    int col = w * 64 + ct * 32 + n;
    short8 bfrag[4];
#pragma unroll
    for (int c = 0; c < 4; ++c) {
#pragma unroll
      for (int j = 0; j < 8; ++j)
        bfrag[c][j] = (short)f2bf(w1[(c * 16 + half * 8 + j) * 256 + col]);
    }
    floatx16 acc;
#pragma unroll
    for (int i = 0; i < 16; ++i) acc[i] = 0.f;
    acc = __builtin_amdgcn_mfma_f32_32x32x16_bf16(a[0], bfrag[0], acc, 0, 0, 0);
    acc = __builtin_amdgcn_mfma_f32_32x32x16_bf16(a[1], bfrag[1], acc, 0, 0, 0);
    acc = __builtin_amdgcn_mfma_f32_32x32x16_bf16(a[2], bfrag[2], acc, 0, 0, 0);
    acc = __builtin_amdgcn_mfma_f32_32x32x16_bf16(a[3], bfrag[3], acc, 0, 0, 0);
    float bias = b1[col];
#pragma unroll
    for (int j = 0; j < 4; ++j) {          // jp_local
      float s = 0.f;
#pragma unroll
      for (int rr = 0; rr < 4; ++rr) {
        float xg = acc[j * 4 + rr] + bias;
        s += 0.5f * xg * (1.f + erff(xg * 0.70710678118654752f));
      }
      s += __shfl_xor(s, 32);              // combine lane-halves (t 0..3 | 4..7)
      if (half == 0)
        Gavg[(gbase + j) * 256 + col] = s * 0.125f;
    }
  }
}

// ---------------- pool = mean_t(tok2) + Gavg @ W2 + b2 (FF2 folded 8x by linearity) ----------------
__global__ void __launch_bounds__(256) k_pool2(const float* __restrict__ Gavg,
                        const bf16* __restrict__ tok2, const float* __restrict__ w2,
                        const float* __restrict__ b2, float* __restrict__ pool) {
  __shared__ __align__(16) float sG[18 * 256];     // 18.4 KB
  __shared__ __align__(16) float sRed[4 * 18 * 64]; // 18.4 KB
  int blk = blockIdx.x;
  int b = blk / 128;
  int rem = blk % 128;
  int ch = rem >> 1, jph = rem & 1;
  int tid = threadIdx.x;
  size_t grow0 = ((size_t)(b * 64 + ch) * 36 + jph * 18) * 256;
  for (int e = tid; e < 1152; e += 256) {          // 18 rows x 64 float4
    int row = e >> 6, c4 = e & 63;
    *(float4*)&sG[row * 256 + c4 * 4] = *(const float4*)&Gavg[grow0 + row * 256 + c4 * 4];
  }
  __syncthreads();
  int kg = tid >> 6, dd = tid & 63;
  float acc[18];
#pragma unroll
  for (int i = 0; i < 18; ++i) acc[i] = 0.f;
  for (int k4 = 0; k4 < 16; ++k4) {
    int k = kg * 64 + k4 * 4;
    float w0 = w2[(k + 0) * 64 + dd];
    float w1 = w2[(k + 1) * 64 + dd];
    float w2v = w2[(k + 2) * 64 + dd];
    float w3 = w2[(k + 3) * 64 + dd];
#pragma unroll
    for (int i = 0; i < 18; ++i) {
      float4 gf = *(const float4*)&sG[i * 256 + k];   // wave-wide broadcast
      acc[i] += gf.x * w0 + gf.y * w1 + gf.z * w2v + gf.w * w3;
    }
  }
#pragma unroll
  for (int i = 0; i < 18; ++i) sRed[(kg * 18 + i) * 64 + dd] = acc[i];
  __syncthreads();
  for (int o = tid; o < 1152; o += 256) {
    int jp18 = o >> 6, d2 = o & 63;
    float gsum = sRed[(0 * 18 + jp18) * 64 + d2] + sRed[(1 * 18 + jp18) * 64 + d2]
               + sRed[(2 * 18 + jp18) * 64 + d2] + sRed[(3 * 18 + jp18) * 64 + d2];
    int p = (jph * 18 + jp18) * 64 + d2;
    size_t tbase = (size_t)b * 1179648 + (size_t)ch * 18432 + p;
    float ts = 0.f;
#pragma unroll
    for (int t = 0; t < 8; ++t) ts += bf2f(tok2[tbase + t * 2304]);
    pool[((size_t)(b * 64 + ch)) * HW + p] = ts * 0.125f + gsum + b2[d2];
  }
}

// ---------------- conv(5x5,pad2) + global-avg-pool folded ----------------
__global__ void __launch_bounds__(256) k_convsum(const float* __restrict__ pool,
                                                 const float* __restrict__ x,
                                                 const float* __restrict__ w,
                                                 float* __restrict__ partial) {
  int blk = blockIdx.x;          // b*65 + ch
  int b = blk / 65, ch = blk % 65;
  int tid = threadIdx.x;
  __shared__ float cls[25];
  __shared__ float red[256];
  if (tid < 25) {
    int ry = tid / 5, rx = tid % 5;
    int kh0 = (ry <= 2) ? 0 : (ry == 3 ? 1 : 2);
    int kh1 = (ry >= 2) ? 4 : (ry == 1 ? 3 : 2);
    int kw0 = (rx <= 2) ? 0 : (rx == 3 ? 1 : 2);
    int kw1 = (rx >= 2) ? 4 : (rx == 1 ? 3 : 2);
    float s = 0.f;
    for (int kh = kh0; kh <= kh1; ++kh)
      for (int kw = kw0; kw <= kw1; ++kw)
        s += w[ch * 25 + kh * 5 + kw];
    cls[tid] = s;
  }
  __syncthreads();
  const float* pc = (ch < 64) ? (pool + ((size_t)(b * 64 + ch)) * HW)
                              : (x + (size_t)b * 3 * S_ + 2 * S_);
  float acc = 0.f;
#pragma unroll
  for (int e = tid; e < HW; e += 256) {
    int iy = e / 48, ix = e % 48;
    int ry = (iy == 0) ? 0 : (iy == 1) ? 1 : (iy <= 45) ? 2 : (iy == 46) ? 3 : 4;
    int rx = (ix == 0) ? 0 : (ix == 1) ? 1 : (ix <= 45) ? 2 : (ix == 46) ? 3 : 4;
    acc += pc[e] * cls[ry * 5 + rx];
  }
  red[tid] = acc;
  __syncthreads();
  for (int s = 128; s; s >>= 1) {
    if (tid < s) red[tid] += red[tid + s];
    __syncthreads();
  }
  if (!tid) partial[blk] = red[0];
}

// ---------------- reduce 65 channel sums per b + readout ----------------
__global__ void k_final(const float* __restrict__ partial, const float* __restrict__ tgt_b,
                        const float* __restrict__ rd_w, const float* __restrict__ rd_b,
                        float* __restrict__ out) {
  int b = blockIdx.x;
  int lane = threadIdx.x;
  float s = (lane < 65) ? partial[b * 65 + lane] : 0.f;
  for (int off = 32; off; off >>= 1) s += __shfl_down(s, off, 64);
  __shared__ float r2;
  if (lane == 64) r2 = s;
  __syncthreads();
  if (!lane) {
    float tot = s + r2;
    float mean = tot / 2304.f + tgt_b[0];
    out[b] = mean * rd_w[0] + rd_b[0];
  }
}

extern "C" void kernel_launch(void* const* d_in, const int* in_sizes, int n_in,
                              void* d_out, int out_size, void* d_ws, size_t ws_size,
                              hipStream_t stream) {
  const float* x     = (const float*)d_in[0];
  const float* pre_w = (const float*)d_in[1];
  const float* pre_b = (const float*)d_in[2];
  const float* ln1_g = (const float*)d_in[3];
  const float* ln1_b = (const float*)d_in[4];
  const float* wq    = (const float*)d_in[5];
  const float* wk    = (const float*)d_in[6];
  const float* wv    = (const float*)d_in[7];
  const float* wo    = (const float*)d_in[8];
  const float* bo    = (const float*)d_in[9];
  const float* proj  = (const float*)d_in[10];
  const float* ln2_g = (const float*)d_in[11];
  const float* ln2_b = (const float*)d_in[12];
  const float* ff_w1 = (const float*)d_in[13];
  const float* ff_b1 = (const float*)d_in[14];
  const float* ff_w2 = (const float*)d_in[15];
  const float* ff_b2 = (const float*)d_in[16];
  const float* tgt_w = (const float*)d_in[17];
  const float* tgt_b = (const float*)d_in[18];
  const float* rd_w  = (const float*)d_in[19];
  const float* rd_b  = (const float*)d_in[20];
  float* out = (float*)d_out;

  float* ws = (float*)d_ws;
  // 0 tok(bf16 half) | 1 v(bf16 half) | 2 q(bf16 half) -> Gavg+pool | 3 k(bf16)/attnb(bf16)
  // 4-5 h(bf16 half at 4) -> kp(f32 raw, 2 units) -> h2(bf16 at 4) | 6 qpb | 7 kpb
  // 8 ckv(f32) -> tok2(bf16) | smalls @ 9*BSD+147456
  bf16*  tok   = (bf16*)ws;
  bf16*  v     = (bf16*)(ws + (size_t)BSD);
  bf16*  q     = (bf16*)(ws + 2 * (size_t)BSD);
  float* Gavg  = ws + 2 * (size_t)BSD;          // q dead after k_feat
  float* pool  = Gavg + 1179648;                // 294912 floats
  bf16*  k     = (bf16*)(ws + 3 * (size_t)BSD);
  bf16*  h     = (bf16*)(ws + 4 * (size_t)BSD); // LN1 out; dead after k_qkv
  float* kp    = ws + 4 * (size_t)BSD;          // 2 BSD raw dash; dead after k_csfin
  bf16*  qpb   = (bf16*)(ws + 6 * (size_t)BSD); // BHSM bf16
  bf16*  kpb   = (bf16*)(ws + 7 * (size_t)BSD); // BHSM bf16
  float* ckv   = ws + 8 * (size_t)BSD;          // 2506752 floats; dead after k_attn
  bf16*  tok2  = (bf16*)(ws + 8 * (size_t)BSD); // written by k_wo_ln (ckv dead)
  bf16*  attnb = k;                             // k dead after k_feat
  bf16*  h2    = h;                             // kp dead after k_csfin
  float* smalls = ws + 9 * (size_t)BSD + 147456;
  float* diagk = smalls;                        // 147456
  float* part  = diagk + BHS;                   // 4608 used (18432 reserved)
  float* gmax  = part + BHSM / 256;             // 1
  float* partial = gmax + 64;                   // 130 (256 reserved)
  float* segsum  = partial + 256;               // BH*NSEG*STATE = 78336

  k_preln<<<dim3(BS / 4), dim3(256), 0, stream>>>(x, pre_w, pre_b, ln1_g, ln1_b, tok, h);
  k_qkv<<<dim3(BS / 32), dim3(192), 0, stream>>>(h, wq, wk, wv, q, k, v);
  k_feat<<<dim3(BHS / 128), dim3(256), 0, stream>>>(q, k, proj, qpb, kp, diagk, part);
  k_maxred<<<dim3(1), dim3(256), 0, stream>>>(part, gmax);
  k_csfin<<<dim3(BH * NC), dim3(256), 0, stream>>>(diagk, gmax, v, kp, kpb, ckv);
  k_scan1<<<dim3(BH * NSEG * STATE / 256), dim3(256), 0, stream>>>(ckv, segsum);
  k_scan2<<<dim3(BH * STATE / 256), dim3(256), 0, stream>>>(segsum);
  k_scan3<<<dim3(BH * NSEG * STATE / 256), dim3(256), 0, stream>>>(ckv, segsum);
  k_attn<<<dim3(BH * NC / 4), dim3(256), 0, stream>>>(qpb, kpb, v, ckv, attnb);
  k_wo_ln<<<dim3(BS / 32), dim3(128), 0, stream>>>(attnb, wo, bo, tok, ln2_g, ln2_b, tok2, h2);
  k_ffg<<<dim3(B_ * 64 * 9), dim3(256), 0, stream>>>(h2, ff_w1, ff_b1, Gavg);
  k_pool2<<<dim3(B_ * 64 * 2), dim3(256), 0, stream>>>(Gavg, tok2, ff_w2, ff_b2, pool);
  k_convsum<<<dim3(B_ * 65), dim3(256), 0, stream>>>(pool, x, tgt_w, partial);
  k_final<<<dim3(B_), dim3(128), 0, stream>>>(partial, tgt_b, rd_w, rd_b, out);
}

// Round 19
// 210.893 us; speedup vs baseline: 1.2503x; 1.0165x over previous
//
#include <hip/hip_runtime.h>
#include <hip/hip_bf16.h>
#include <math.h>

typedef __hip_bfloat16 bf16;
typedef __attribute__((ext_vector_type(8))) short short8;
typedef __attribute__((ext_vector_type(16))) float floatx16;

// Problem constants
constexpr int B_   = 2;
constexpr int T_   = 8;
constexpr int HW   = 48 * 48;          // 2304
constexpr int S_   = T_ * HW;          // 18432
constexpr int D_   = 64;
constexpr int NH   = 4;
constexpr int DH   = 16;
constexpr int M_   = 32;
constexpr int BS   = B_ * S_;          // 36864 tokens
constexpr int BSD  = BS * D_;          // 2359296
constexpr int BH   = B_ * NH;          // 8 sequences
constexpr int BHS  = BH * S_;          // 147456 rows
constexpr int BHSM = BHS * M_;         // 4718592
constexpr int CHUNK = 32;
constexpr int NC   = S_ / CHUNK;       // 576 chunks per sequence
constexpr int NSEG = 18;               // scan segments
constexpr int SEGLEN = 32;             // NC = NSEG * SEGLEN
constexpr int STATE = M_ * DH + M_;    // 544 floats of scan state
constexpr float DN = 0.5f;                         // 16^-0.25
constexpr float RATIO = 0.17677669529663687f;      // 32^-0.5

__device__ __forceinline__ unsigned short f2bf(float f) {
  bf16 h = __float2bfloat16(f);
  return *reinterpret_cast<unsigned short*>(&h);
}
__device__ __forceinline__ float bf2f(bf16 v) { return __bfloat162float(v); }

// ---------------- fused: 1x1x1 conv3d + softplus + LayerNorm1 (tok, h out bf16) ----------------
__global__ void k_preln(const float* __restrict__ x, const float* __restrict__ pw,
                        const float* __restrict__ pb, const float* __restrict__ g,
                        const float* __restrict__ bb,
                        bf16* __restrict__ tok, bf16* __restrict__ h) {
  int token = blockIdx.x * 4 + (threadIdx.x >> 6);
  int lane = threadIdx.x & 63;
  int f = token * 64 + lane;          // flat over B*D*S
  int b = f / (D_ * S_);
  int r = f % (D_ * S_);
  int d = r / S_;
  int pos = r % S_;
  const float* xb = x + b * 3 * S_ + pos;
  float a = xb[0] * pw[d * 3 + 0] + xb[S_] * pw[d * 3 + 1] + xb[2 * S_] * pw[d * 3 + 2]
          + pb[d];
  float t = fmaxf(a, 0.f) + log1pf(expf(-fabsf(a)));  // softplus
  tok[f] = __float2bfloat16(t);
  float s1 = t, s2 = t * t;
  for (int off = 32; off; off >>= 1) {
    s1 += __shfl_xor(s1, off);
    s2 += __shfl_xor(s2, off);
  }
  float mu = s1 * (1.f / 64.f);
  float var = s2 * (1.f / 64.f) - mu * mu;
  float rs = rsqrtf(var + 1e-5f);
  h[f] = __float2bfloat16((t - mu) * rs * g[lane] + bb[lane]);
}

// ---------------- QKV projections via MFMA: 3 waves = {wq,wk,wv}; q,k,v out bf16 ----------------
__global__ void __launch_bounds__(192) k_qkv(const bf16* __restrict__ h,
                      const float* __restrict__ wq, const float* __restrict__ wk,
                      const float* __restrict__ wv,
                      bf16* __restrict__ q, bf16* __restrict__ k, bf16* __restrict__ v) {
  int tid = threadIdx.x;
  int w = tid >> 6;                 // wave -> matrix
  int L = tid & 63;
  int half = L >> 5;
  int n = L & 31;
  int tbase = blockIdx.x * 32;
  const float* wm = (w == 0) ? wq : (w == 1) ? wk : wv;
  bf16* outm = (w == 0) ? q : (w == 1) ? k : v;

  short8 a[4];
  {
    const bf16* hrow = h + (size_t)(tbase + n) * 64 + half * 8;
#pragma unroll
    for (int c = 0; c < 4; ++c) a[c] = *(const short8*)(hrow + c * 16);
  }
#pragma unroll
  for (int ct = 0; ct < 2; ++ct) {
    int col = ct * 32 + n;
    short8 bfrag[4];
#pragma unroll
    for (int c = 0; c < 4; ++c) {
#pragma unroll
      for (int j = 0; j < 8; ++j)
        bfrag[c][j] = (short)f2bf(wm[(c * 16 + half * 8 + j) * 64 + col]);
    }
    floatx16 acc;
#pragma unroll
    for (int i = 0; i < 16; ++i) acc[i] = 0.f;
    acc = __builtin_amdgcn_mfma_f32_32x32x16_bf16(a[0], bfrag[0], acc, 0, 0, 0);
    acc = __builtin_amdgcn_mfma_f32_32x32x16_bf16(a[1], bfrag[1], acc, 0, 0, 0);
    acc = __builtin_amdgcn_mfma_f32_32x32x16_bf16(a[2], bfrag[2], acc, 0, 0, 0);
    acc = __builtin_amdgcn_mfma_f32_32x32x16_bf16(a[3], bfrag[3], acc, 0, 0, 0);
    int head = col >> 4, di = col & 15;
#pragma unroll
    for (int r = 0; r < 16; ++r) {
      int row = (r & 3) + 8 * (r >> 2) + 4 * half;
      int token = tbase + row;
      int b = token / S_, s = token % S_;
      outm[((size_t)(b * NH + head) * S_ + s) * DH + di] = __float2bfloat16(acc[r]);
    }
  }
}

// ---------------- feature map via MFMA (q,k bf16 in): qp bf16 + raw dash_k fp32 + diagk + max ----
__global__ void __launch_bounds__(256) k_feat(const bf16* __restrict__ q,
                      const bf16* __restrict__ k, const float* __restrict__ proj,
                      bf16* __restrict__ qpb, float* __restrict__ kp,
                      float* __restrict__ diagk, float* __restrict__ part) {
  int tid = threadIdx.x;
  int w = tid >> 6;
  int L = tid & 63;
  int half = L >> 5;
  int n = L & 31;
  int rowbase = blockIdx.x * 128 + w * 32;

  short8 qs = *(const short8*)(q + (size_t)(rowbase + n) * 16 + half * 8);
  short8 ks = *(const short8*)(k + (size_t)(rowbase + n) * 16 + half * 8);
  short8 aq, ak, bp;
  float dq = 0.f, dk = 0.f;
#pragma unroll
  for (int j = 0; j < 8; ++j) {
    float qf = __uint_as_float(((unsigned)(unsigned short)qs[j]) << 16) * DN;  // x0.5 exact
    float kf = __uint_as_float(((unsigned)(unsigned short)ks[j]) << 16) * DN;
    dq += qf * qf; dk += kf * kf;
    aq[j] = (short)f2bf(qf);
    ak[j] = (short)f2bf(kf);
    bp[j] = (short)f2bf(proj[n * 16 + half * 8 + j]);   // B[d][m=n]
  }
  dq += __shfl_xor(dq, 32);
  dk += __shfl_xor(dk, 32);
  dq *= 0.5f; dk *= 0.5f;

  floatx16 Pq, Pk;
#pragma unroll
  for (int i = 0; i < 16; ++i) { Pq[i] = 0.f; Pk[i] = 0.f; }
  Pq = __builtin_amdgcn_mfma_f32_32x32x16_bf16(aq, bp, Pq, 0, 0, 0);
  Pk = __builtin_amdgcn_mfma_f32_32x32x16_bf16(ak, bp, Pk, 0, 0, 0);

  float bmax = -3.4e38f;
#pragma unroll
  for (int r = 0; r < 16; ++r) {
    int i = (r & 3) + 8 * (r >> 2) + 4 * half;
    kp[(size_t)(rowbase + i) * 32 + n] = Pk[r];
    bmax = fmaxf(bmax, Pk[r]);
  }
  if (L < 32) diagk[rowbase + n] = dk;
  for (int off = 32; off; off >>= 1) bmax = fmaxf(bmax, __shfl_xor(bmax, off));
  if (L == 0) part[blockIdx.x * 4 + w] = bmax;

#pragma unroll
  for (int r = 0; r < 16; ++r) {
    int i = (r & 3) + 8 * (r >> 2) + 4 * half;
    float mx = Pq[r];
    for (int off = 16; off; off >>= 1) mx = fmaxf(mx, __shfl_xor(mx, off, 32));
    float dqi = __shfl(dq, i, 64);          // row i's dq lives on lane i (<32)
    float val = RATIO * (expf(Pq[r] - dqi - mx) + 1e-4f);
    qpb[(size_t)(rowbase + i) * 32 + n] = __float2bfloat16(val);
  }
}

__global__ void k_maxred(const float* __restrict__ part, float* __restrict__ gmax) {
  float m = -3.4e38f;
  for (int i = threadIdx.x; i < BHS / 32; i += 256) m = fmaxf(m, part[i]);
  __shared__ float red[256];
  red[threadIdx.x] = m;
  __syncthreads();
  for (int s = 128; s; s >>= 1) {
    if (threadIdx.x < s) red[threadIdx.x] = fmaxf(red[threadIdx.x], red[threadIdx.x + s]);
    __syncthreads();
  }
  if (!threadIdx.x) gmax[0] = red[0];
}

// ---------------- kp-finalize (raw fp32 -> bf16 kpb) + per-chunk sums (LDS); v bf16 ----------------
__global__ void __launch_bounds__(256) k_csfin(const float* __restrict__ diagk,
                      const float* __restrict__ gmax, const bf16* __restrict__ v,
                      const float* __restrict__ kp, bf16* __restrict__ kpb,
                      float* __restrict__ ckv) {
  __shared__ __align__(16) float sKp[CHUNK * 32];
  __shared__ __align__(16) float sVc[CHUNK * 16];
  int blk = blockIdx.x;
  int bh = blk / NC, c = blk % NC;
  int tid = threadIdx.x;
  int base = bh * S_ + c * CHUNK;
  float gm = gmax[0];
  {
    int row = tid >> 3, m4 = tid & 7;            // 32 rows x 8 float4
    float4 dash = *(const float4*)&kp[(size_t)(base + row) * 32 + m4 * 4];
    float dg = diagk[base + row] + gm;
    float4 fin;
    fin.x = RATIO * (expf(dash.x - dg) + 1e-4f);
    fin.y = RATIO * (expf(dash.y - dg) + 1e-4f);
    fin.z = RATIO * (expf(dash.z - dg) + 1e-4f);
    fin.w = RATIO * (expf(dash.w - dg) + 1e-4f);
    *(float4*)&sKp[row * 32 + m4 * 4] = fin;
    uint2 u;
    u.x = (unsigned)f2bf(fin.x) | ((unsigned)f2bf(fin.y) << 16);
    u.y = (unsigned)f2bf(fin.z) | ((unsigned)f2bf(fin.w) << 16);
    *(uint2*)&kpb[(size_t)(base + row) * 32 + m4 * 4] = u;
  }
  if (tid < 128) {                               // V: 32 rows x 4 groups of 4 bf16
    int row = tid >> 2, c4 = tid & 3;
    const bf16* vr = v + (size_t)(base + row) * 16 + c4 * 4;
    sVc[row * 16 + c4 * 4 + 0] = bf2f(vr[0]);
    sVc[row * 16 + c4 * 4 + 1] = bf2f(vr[1]);
    sVc[row * 16 + c4 * 4 + 2] = bf2f(vr[2]);
    sVc[row * 16 + c4 * 4 + 3] = bf2f(vr[3]);
  }
  __syncthreads();
  int m0 = tid >> 4, d0 = tid & 15;
  int m1 = m0 + 16;
  float a0 = 0.f, a1 = 0.f, az0 = 0.f, az1 = 0.f;
  for (int t = 0; t < CHUNK; ++t) {
    float k0 = sKp[t * 32 + m0];
    float k1 = sKp[t * 32 + m1];
    float vv = sVc[t * 16 + d0];
    a0 += k0 * vv;
    a1 += k1 * vv;
    if (d0 == 0) { az0 += k0; az1 += k1; }
  }
  float* outp = ckv + (size_t)blk * STATE;
  outp[m0 * 16 + d0] = a0;
  outp[m1 * 16 + d0] = a1;
  if (d0 == 0) { outp[512 + m0] = az0; outp[512 + m1] = az1; }
}

// ---------------- 3-phase segmented exclusive scan over chunks ----------------
__global__ void k_scan1(const float* __restrict__ ckv, float* __restrict__ segsum) {
  int idx = blockIdx.x * 256 + threadIdx.x;
  int c = idx % STATE;
  int rem = idx / STATE;
  int seg = rem % NSEG;
  int bh = rem / NSEG;
  size_t base = ((size_t)bh * NC + seg * SEGLEN) * STATE + c;
  float s = 0.f;
#pragma unroll 8
  for (int i = 0; i < SEGLEN; ++i) s += ckv[base + (size_t)i * STATE];
  segsum[idx] = s;
}

__global__ void k_scan2(float* __restrict__ segsum) {
  int idx = blockIdx.x * 256 + threadIdx.x;      // BH*STATE = 4352
  int c = idx % STATE;
  int bh = idx / STATE;
  float tb[NSEG];
#pragma unroll
  for (int s = 0; s < NSEG; ++s)
    tb[s] = segsum[((size_t)bh * NSEG + s) * STATE + c];
  float run = 0.f;
#pragma unroll
  for (int s = 0; s < NSEG; ++s) {
    segsum[((size_t)bh * NSEG + s) * STATE + c] = run;
    run += tb[s];
  }
}

__global__ void k_scan3(float* __restrict__ ckv, const float* __restrict__ segsum) {
  int idx = blockIdx.x * 256 + threadIdx.x;
  int c = idx % STATE;
  int rem = idx / STATE;
  int seg = rem % NSEG;
  int bh = rem / NSEG;
  float run = segsum[idx];
  size_t base = ((size_t)bh * NC + seg * SEGLEN) * STATE + c;
  for (int i0 = 0; i0 < SEGLEN; i0 += 8) {
    float tb[8];
#pragma unroll
    for (int j = 0; j < 8; ++j) tb[j] = ckv[base + (size_t)(i0 + j) * STATE];
#pragma unroll
    for (int j = 0; j < 8; ++j) {
      ckv[base + (size_t)(i0 + j) * STATE] = run;
      run += tb[j];
    }
  }
}

// ---------------- within-chunk causal attention via MFMA (CHUNK=32; 4 chunks/block) ----------------
__global__ void __launch_bounds__(256) k_attn(const bf16* __restrict__ qpb,
                                              const bf16* __restrict__ kpb,
                                              const bf16* __restrict__ v,
                                              const float* __restrict__ ckv,
                                              bf16* __restrict__ attn) {
  __shared__ __align__(16) float sP[4][32 * 33 + 4];
  int tid = threadIdx.x;
  int w = tid >> 6;                 // wave -> chunk
  int L = tid & 63;
  int half = L >> 5;
  int n = L & 31;
  int chunk = blockIdx.x * 4 + w;
  int bh = chunk / NC, c = chunk % NC;
  int base = bh * S_ + c * CHUNK;

  short8 a1 = *(const short8*)(qpb + (size_t)(base + n) * 32 + half * 8);
  short8 a2 = *(const short8*)(qpb + (size_t)(base + n) * 32 + 16 + half * 8);
  short8 b1 = *(const short8*)(kpb + (size_t)(base + n) * 32 + half * 8);
  short8 b2 = *(const short8*)(kpb + (size_t)(base + n) * 32 + 16 + half * 8);

  floatx16 P;
#pragma unroll
  for (int i = 0; i < 16; ++i) P[i] = 0.f;
  P = __builtin_amdgcn_mfma_f32_32x32x16_bf16(a1, b1, P, 0, 0, 0);
  P = __builtin_amdgcn_mfma_f32_32x32x16_bf16(a2, b2, P, 0, 0, 0);

  float* sp = &sP[w][0];
#pragma unroll
  for (int r = 0; r < 16; ++r) {
    int i = (r & 3) + 8 * (r >> 2) + 4 * half;
    sp[i * 33 + n] = (n <= i) ? P[r] : 0.f;
  }
  __syncthreads();
  short8 pa1, pa2;
#pragma unroll
  for (int j = 0; j < 8; ++j) {
    pa1[j] = (short)f2bf(sp[n * 33 + half * 8 + j]);
    pa2[j] = (short)f2bf(sp[n * 33 + 16 + half * 8 + j]);
  }

  const float* cs = ckv + (size_t)chunk * STATE;
  const unsigned short one_bf = f2bf(1.f);
  short8 vb1, vb2, sb1, sb2;
#pragma unroll
  for (int j = 0; j < 8; ++j) {
    int t1 = half * 8 + j, t2 = 16 + half * 8 + j;
    vb1[j] = (n < 16) ? *(const short*)(v + (size_t)(base + t1) * 16 + n)
                      : (short)(n == 16 ? one_bf : 0);
    vb2[j] = (n < 16) ? *(const short*)(v + (size_t)(base + t2) * 16 + n)
                      : (short)(n == 16 ? one_bf : 0);
    float y1 = (n < 16) ? cs[t1 * 16 + n] : (n == 16 ? cs[512 + t1] : 0.f);
    float y2 = (n < 16) ? cs[t2 * 16 + n] : (n == 16 ? cs[512 + t2] : 0.f);
    sb1[j] = (short)f2bf(y1);
    sb2[j] = (short)f2bf(y2);
  }

  floatx16 O;
#pragma unroll
  for (int i = 0; i < 16; ++i) O[i] = 0.f;
  O = __builtin_amdgcn_mfma_f32_32x32x16_bf16(pa1, vb1, O, 0, 0, 0);
  O = __builtin_amdgcn_mfma_f32_32x32x16_bf16(pa2, vb2, O, 0, 0, 0);
  O = __builtin_amdgcn_mfma_f32_32x32x16_bf16(a1, sb1, O, 0, 0, 0);
  O = __builtin_amdgcn_mfma_f32_32x32x16_bf16(a2, sb2, O, 0, 0, 0);

  int srcl = 16 + 32 * half;
  float res[16];
#pragma unroll
  for (int r = 0; r < 16; ++r) {
    float den = __shfl(O[r], srcl, 64);
    res[r] = O[r] / den;
  }
  if (n < 16) {
    int b = bh >> 2, head = bh & 3;
#pragma unroll
    for (int r = 0; r < 16; ++r) {
      int i = (r & 3) + 8 * (r >> 2) + 4 * half;
      attn[((size_t)(b * S_ + c * CHUNK + i)) * 64 + head * 16 + n] = __float2bfloat16(res[r]);
    }
  }
}

// ---------------- attn(bf16) @ wo + bo + residual(bf16) + LayerNorm2; tok2 bf16, h2 bf16 ----------
__global__ void __launch_bounds__(128) k_wo_ln(const bf16* __restrict__ attn,
                        const float* __restrict__ wo, const float* __restrict__ bo,
                        const bf16* __restrict__ tok, const float* __restrict__ g,
                        const float* __restrict__ bb,
                        bf16* __restrict__ tok2, bf16* __restrict__ h2) {
  __shared__ __align__(16) float sC[32 * 68];
  int tid = threadIdx.x;
  int w = tid >> 6;                 // coltile
  int L = tid & 63;
  int half = L >> 5;
  int n = L & 31;
  int tbase = blockIdx.x * 32;

  short8 a[4];
  {
    const bf16* arow = attn + (size_t)(tbase + n) * 64 + half * 8;
#pragma unroll
    for (int c = 0; c < 4; ++c) a[c] = *(const short8*)(arow + c * 16);
  }
  int col = w * 32 + n;
  short8 bfrag[4];
#pragma unroll
  for (int c = 0; c < 4; ++c) {
#pragma unroll
    for (int j = 0; j < 8; ++j)
      bfrag[c][j] = (short)f2bf(wo[(c * 16 + half * 8 + j) * 64 + col]);
  }
  floatx16 acc;
#pragma unroll
  for (int i = 0; i < 16; ++i) acc[i] = 0.f;
  acc = __builtin_amdgcn_mfma_f32_32x32x16_bf16(a[0], bfrag[0], acc, 0, 0, 0);
  acc = __builtin_amdgcn_mfma_f32_32x32x16_bf16(a[1], bfrag[1], acc, 0, 0, 0);
  acc = __builtin_amdgcn_mfma_f32_32x32x16_bf16(a[2], bfrag[2], acc, 0, 0, 0);
  acc = __builtin_amdgcn_mfma_f32_32x32x16_bf16(a[3], bfrag[3], acc, 0, 0, 0);
  float bias = bo[col];
#pragma unroll
  for (int r = 0; r < 16; ++r) {
    int row = (r & 3) + 8 * (r >> 2) + 4 * half;
    sC[row * 68 + col] = acc[r] + bf2f(tok[(size_t)(tbase + row) * 64 + col]) + bias;
  }
  __syncthreads();
  int tg = tid >> 5, cg = tid & 31;
  int c0 = cg * 2, c1 = c0 + 1;
  float g0 = g[c0], g1 = g[c1], be0 = bb[c0], be1 = bb[c1];
#pragma unroll
  for (int i = 0; i < 8; ++i) {
    int lrow = tg * 8 + i;
    int token = tbase + lrow;
    float t0 = sC[lrow * 68 + c0];
    float t1 = sC[lrow * 68 + c1];
    float s1 = t0 + t1, s2 = t0 * t0 + t1 * t1;
    for (int off = 16; off; off >>= 1) {
      s1 += __shfl_xor(s1, off, 32);
      s2 += __shfl_xor(s2, off, 32);
    }
    float mu = s1 * (1.f / 64.f);
    float var = s2 * (1.f / 64.f) - mu * mu;
    float rs = rsqrtf(var + 1e-5f);
    tok2[token * 64 + c0] = __float2bfloat16(t0);
    tok2[token * 64 + c1] = __float2bfloat16(t1);
    h2[token * 64 + c0] = __float2bfloat16((t0 - mu) * rs * g0 + be0);
    h2[token * 64 + c1] = __float2bfloat16((t1 - mu) * rs * g1 + be1);
  }
}

// ---------------- FF1 + Gavg fused via MFMA (h2 bf16 in) ----------------
__global__ void __launch_bounds__(256) k_ffg(const bf16* __restrict__ h2,
                                             const float* __restrict__ w1,
                                             const float* __restrict__ b1,
                                             float* __restrict__ Gavg) {
  int tid = threadIdx.x;
  int w = tid >> 6;
  int L = tid & 63;
  int half = L >> 5;
  int n = L & 31;
  int blk = blockIdx.x;                 // B*64*9 = 1152
  int b = blk / 576;
  int rem = blk % 576;
  int ch = rem / 9;
  int jp0 = (rem % 9) * 4;
  int token_n = b * 18432 + ch * 288 + (n & 7) * 36 + jp0 + (n >> 3);

  short8 a[4];
  {
    const bf16* hrow = h2 + (size_t)token_n * 64 + half * 8;
#pragma unroll
    for (int c = 0; c < 4; ++c) a[c] = *(const short8*)(hrow + c * 16);
  }
  size_t gbase = ((size_t)(b * 64 + ch) * 36 + jp0);
#pragma unroll
  for (int ct = 0; ct < 2; ++ct) {
    int col = w * 64 + ct * 32 + n;
    short8 bfrag[4];
#pragma unroll
    for (int c = 0; c < 4; ++c) {
#pragma unroll
      for (int j = 0; j < 8; ++j)
        bfrag[c][j] = (short)f2bf(w1[(c * 16 + half * 8 + j) * 256 + col]);
    }
    floatx16 acc;
#pragma unroll
    for (int i = 0; i < 16; ++i) acc[i] = 0.f;
    acc = __builtin_amdgcn_mfma_f32_32x32x16_bf16(a[0], bfrag[0], acc, 0, 0, 0);
    acc = __builtin_amdgcn_mfma_f32_32x32x16_bf16(a[1], bfrag[1], acc, 0, 0, 0);
    acc = __builtin_amdgcn_mfma_f32_32x32x16_bf16(a[2], bfrag[2], acc, 0, 0, 0);
    acc = __builtin_amdgcn_mfma_f32_32x32x16_bf16(a[3], bfrag[3], acc, 0, 0, 0);
    float bias = b1[col];
#pragma unroll
    for (int j = 0; j < 4; ++j) {          // jp_local
      float s = 0.f;
#pragma unroll
      for (int rr = 0; rr < 4; ++rr) {
        float xg = acc[j * 4 + rr] + bias;
        s += 0.5f * xg * (1.f + erff(xg * 0.70710678118654752f));
      }
      s += __shfl_xor(s, 32);              // combine lane-halves (t 0..3 | 4..7)
      if (half == 0)
        Gavg[(gbase + j) * 256 + col] = s * 0.125f;
    }
  }
}

// ---------------- pool = mean_t(tok2) + Gavg @ W2 + b2 (FF2 folded 8x by linearity) ----------------
__global__ void __launch_bounds__(256) k_pool2(const float* __restrict__ Gavg,
                        const bf16* __restrict__ tok2, const float* __restrict__ w2,
                        const float* __restrict__ b2, float* __restrict__ pool) {
  __shared__ __align__(16) float sG[18 * 256];     // 18.4 KB
  __shared__ __align__(16) float sRed[4 * 18 * 64]; // 18.4 KB
  int blk = blockIdx.x;
  int b = blk / 128;
  int rem = blk % 128;
  int ch = rem >> 1, jph = rem & 1;
  int tid = threadIdx.x;
  size_t grow0 = ((size_t)(b * 64 + ch) * 36 + jph * 18) * 256;
  for (int e = tid; e < 1152; e += 256) {          // 18 rows x 64 float4
    int row = e >> 6, c4 = e & 63;
    *(float4*)&sG[row * 256 + c4 * 4] = *(const float4*)&Gavg[grow0 + row * 256 + c4 * 4];
  }
  __syncthreads();
  int kg = tid >> 6, dd = tid & 63;
  float acc[18];
#pragma unroll
  for (int i = 0; i < 18; ++i) acc[i] = 0.f;
  for (int k4 = 0; k4 < 16; ++k4) {
    int k = kg * 64 + k4 * 4;
    float w0 = w2[(k + 0) * 64 + dd];
    float w1 = w2[(k + 1) * 64 + dd];
    float w2v = w2[(k + 2) * 64 + dd];
    float w3 = w2[(k + 3) * 64 + dd];
#pragma unroll
    for (int i = 0; i < 18; ++i) {
      float4 gf = *(const float4*)&sG[i * 256 + k];   // wave-wide broadcast
      acc[i] += gf.x * w0 + gf.y * w1 + gf.z * w2v + gf.w * w3;
    }
  }
#pragma unroll
  for (int i = 0; i < 18; ++i) sRed[(kg * 18 + i) * 64 + dd] = acc[i];
  __syncthreads();
  for (int o = tid; o < 1152; o += 256) {
    int jp18 = o >> 6, d2 = o & 63;
    float gsum = sRed[(0 * 18 + jp18) * 64 + d2] + sRed[(1 * 18 + jp18) * 64 + d2]
               + sRed[(2 * 18 + jp18) * 64 + d2] + sRed[(3 * 18 + jp18) * 64 + d2];
    int p = (jph * 18 + jp18) * 64 + d2;
    size_t tbase = (size_t)b * 1179648 + (size_t)ch * 18432 + p;
    float ts = 0.f;
#pragma unroll
    for (int t = 0; t < 8; ++t) ts += bf2f(tok2[tbase + t * 2304]);
    pool[((size_t)(b * 64 + ch)) * HW + p] = ts * 0.125f + gsum + b2[d2];
  }
}

// ---------------- conv(5x5,pad2) + global-avg-pool folded ----------------
__global__ void __launch_bounds__(256) k_convsum(const float* __restrict__ pool,
                                                 const float* __restrict__ x,
                                                 const float* __restrict__ w,
                                                 float* __restrict__ partial) {
  int blk = blockIdx.x;          // b*65 + ch
  int b = blk / 65, ch = blk % 65;
  int tid = threadIdx.x;
  __shared__ float cls[25];
  __shared__ float red[256];
  if (tid < 25) {
    int ry = tid / 5, rx = tid % 5;
    int kh0 = (ry <= 2) ? 0 : (ry == 3 ? 1 : 2);
    int kh1 = (ry >= 2) ? 4 : (ry == 1 ? 3 : 2);
    int kw0 = (rx <= 2) ? 0 : (rx == 3 ? 1 : 2);
    int kw1 = (rx >= 2) ? 4 : (rx == 1 ? 3 : 2);
    float s = 0.f;
    for (int kh = kh0; kh <= kh1; ++kh)
      for (int kw = kw0; kw <= kw1; ++kw)
        s += w[ch * 25 + kh * 5 + kw];
    cls[tid] = s;
  }
  __syncthreads();
  const float* pc = (ch < 64) ? (pool + ((size_t)(b * 64 + ch)) * HW)
                              : (x + (size_t)b * 3 * S_ + 2 * S_);
  float acc = 0.f;
#pragma unroll
  for (int e = tid; e < HW; e += 256) {
    int iy = e / 48, ix = e % 48;
    int ry = (iy == 0) ? 0 : (iy == 1) ? 1 : (iy <= 45) ? 2 : (iy == 46) ? 3 : 4;
    int rx = (ix == 0) ? 0 : (ix == 1) ? 1 : (ix <= 45) ? 2 : (ix == 46) ? 3 : 4;
    acc += pc[e] * cls[ry * 5 + rx];
  }
  red[tid] = acc;
  __syncthreads();
  for (int s = 128; s; s >>= 1) {
    if (tid < s) red[tid] += red[tid + s];
    __syncthreads();
  }
  if (!tid) partial[blk] = red[0];
}

// ---------------- reduce 65 channel sums per b + readout ----------------
__global__ void k_final(const float* __restrict__ partial, const float* __restrict__ tgt_b,
                        const float* __restrict__ rd_w, const float* __restrict__ rd_b,
                        float* __restrict__ out) {
  int b = blockIdx.x;
  int lane = threadIdx.x;
  float s = (lane < 65) ? partial[b * 65 + lane] : 0.f;
  for (int off = 32; off; off >>= 1) s += __shfl_down(s, off, 64);
  __shared__ float r2;
  if (lane == 64) r2 = s;
  __syncthreads();
  if (!lane) {
    float tot = s + r2;
    float mean = tot / 2304.f + tgt_b[0];
    out[b] = mean * rd_w[0] + rd_b[0];
  }
}

extern "C" void kernel_launch(void* const* d_in, const int* in_sizes, int n_in,
                              void* d_out, int out_size, void* d_ws, size_t ws_size,
                              hipStream_t stream) {
  const float* x     = (const float*)d_in[0];
  const float* pre_w = (const float*)d_in[1];
  const float* pre_b = (const float*)d_in[2];
  const float* ln1_g = (const float*)d_in[3];
  const float* ln1_b = (const float*)d_in[4];
  const float* wq    = (const float*)d_in[5];
  const float* wk    = (const float*)d_in[6];
  const float* wv    = (const float*)d_in[7];
  const float* wo    = (const float*)d_in[8];
  const float* bo    = (const float*)d_in[9];
  const float* proj  = (const float*)d_in[10];
  const float* ln2_g = (const float*)d_in[11];
  const float* ln2_b = (const float*)d_in[12];
  const float* ff_w1 = (const float*)d_in[13];
  const float* ff_b1 = (const float*)d_in[14];
  const float* ff_w2 = (const float*)d_in[15];
  const float* ff_b2 = (const float*)d_in[16];
  const float* tgt_w = (const float*)d_in[17];
  const float* tgt_b = (const float*)d_in[18];
  const float* rd_w  = (const float*)d_in[19];
  const float* rd_b  = (const float*)d_in[20];
  float* out = (float*)d_out;

  float* ws = (float*)d_ws;
  // 0 tok(bf16 half) | 1 v(bf16 half) | 2 q(bf16 half) -> Gavg+pool | 3 k(bf16)/attnb(bf16)
  // 4-5 kp(f32 raw) -> h2(bf16 at 4) | 6 qpb | 7 kpb | 8 ckv(f32) -> tok2(bf16)
  // smalls @ 9*BSD+147456
  bf16*  tok   = (bf16*)ws;
  bf16*  v     = (bf16*)(ws + (size_t)BSD);
  bf16*  q     = (bf16*)(ws + 2 * (size_t)BSD);
  float* Gavg  = ws + 2 * (size_t)BSD;          // q dead after k_feat
  float* pool  = Gavg + 1179648;                // 294912 floats
  bf16*  k     = (bf16*)(ws + 3 * (size_t)BSD);
  bf16*  h     = (bf16*)(ws + 4 * (size_t)BSD); // LN1 out; dead after k_qkv
  float* kp    = ws + 4 * (size_t)BSD;          // 2 BSD raw dash; dead after k_csfin
  bf16*  qpb   = (bf16*)(ws + 6 * (size_t)BSD); // BHSM bf16
  bf16*  kpb   = (bf16*)(ws + 7 * (size_t)BSD); // BHSM bf16
  float* ckv   = ws + 8 * (size_t)BSD;          // 2506752 floats; dead after k_attn
  bf16*  tok2  = (bf16*)(ws + 8 * (size_t)BSD); // written by k_wo_ln (ckv dead)
  bf16*  attnb = k;                             // k dead after k_feat
  bf16*  h2    = h;                             // kp dead after k_csfin
  float* smalls = ws + 9 * (size_t)BSD + 147456;
  float* diagk = smalls;                        // 147456
  float* part  = diagk + BHS;                   // 4608 used (18432 reserved)
  float* gmax  = part + BHSM / 256;             // 1
  float* partial = gmax + 64;                   // 130 (256 reserved)
  float* segsum  = partial + 256;               // BH*NSEG*STATE = 78336

  k_preln<<<dim3(BS / 4), dim3(256), 0, stream>>>(x, pre_w, pre_b, ln1_g, ln1_b, tok, h);
  k_qkv<<<dim3(BS / 32), dim3(192), 0, stream>>>(h, wq, wk, wv, q, k, v);
  k_feat<<<dim3(BHS / 128), dim3(256), 0, stream>>>(q, k, proj, qpb, kp, diagk, part);
  k_maxred<<<dim3(1), dim3(256), 0, stream>>>(part, gmax);
  k_csfin<<<dim3(BH * NC), dim3(256), 0, stream>>>(diagk, gmax, v, kp, kpb, ckv);
  k_scan1<<<dim3(BH * NSEG * STATE / 256), dim3(256), 0, stream>>>(ckv, segsum);
  k_scan2<<<dim3(BH * STATE / 256), dim3(256), 0, stream>>>(segsum);
  k_scan3<<<dim3(BH * NSEG * STATE / 256), dim3(256), 0, stream>>>(ckv, segsum);
  k_attn<<<dim3(BH * NC / 4), dim3(256), 0, stream>>>(qpb, kpb, v, ckv, attnb);
  k_wo_ln<<<dim3(BS / 32), dim3(128), 0, stream>>>(attnb, wo, bo, tok, ln2_g, ln2_b, tok2, h2);
  k_ffg<<<dim3(B_ * 64 * 9), dim3(256), 0, stream>>>(h2, ff_w1, ff_b1, Gavg);
  k_pool2<<<dim3(B_ * 64 * 2), dim3(256), 0, stream>>>(Gavg, tok2, ff_w2, ff_b2, pool);
  k_convsum<<<dim3(B_ * 65), dim3(256), 0, stream>>>(pool, x, tgt_w, partial);
  k_final<<<dim3(B_), dim3(128), 0, stream>>>(partial, tgt_b, rd_w, rd_b, out);
}